// Round 2
// baseline (1773.515 us; speedup 1.0000x reference)
//
#include <hip/hip_runtime.h>
#include <math.h>

// NextIntegerLinkPredictor: N=100k nodes, E=1.6M edges, Q=500k queries,
// F=128, H=256, D=128, fp32 (no fp32 MFMA on CDNA4 -> vector-ALU GEMMs).
//
// Pipeline:
//   CSR build (count -> two-level scan -> fill), dinv = rsqrt(deg+1)
//   conv1: hw = (x@W1)*dinv[row] ; h1 = relu(csr_sum(hw)*dinv + b1)
//   conv2: same with W2
//   z  = h2@Wfc + bfc
//   A  = z@Wd1[0:128] + bd1 ; B = z@Wd1[128:256]   (decoder stage-1 over NODES)
//   fused decoder: per 64 queries, u1 = relu(A[qs]+B[qd]+idiff*wi+sp*ws) built
//   in LDS, u2 = relu(u1@Wd2+bd2), out = sigmoid(u2.Wd3+bd3)  (one kernel)

__device__ __forceinline__ float4 ld4(const float* p){ return *reinterpret_cast<const float4*>(p); }
__device__ __forceinline__ void st4(float* p, float4 v){ *reinterpret_cast<float4*>(p) = v; }

// ---------------- CSR build ----------------
__global__ void k_count(const int* __restrict__ ei, int E, int* __restrict__ counts){
    int e = blockIdx.x * 256 + threadIdx.x;
    if (e < E) atomicAdd(&counts[ei[E + e]], 1);
}

__global__ __launch_bounds__(1024) void k_blocksum(const int* __restrict__ counts, int n,
                                                   int* __restrict__ bsum){
    __shared__ int sb[1024];
    int i = blockIdx.x * 1024 + threadIdx.x;
    sb[threadIdx.x] = (i < n) ? counts[i] : 0;
    __syncthreads();
    for (int off = 512; off > 0; off >>= 1){
        if (threadIdx.x < off) sb[threadIdx.x] += sb[threadIdx.x + off];
        __syncthreads();
    }
    if (threadIdx.x == 0) bsum[blockIdx.x] = sb[0];
}

__global__ void k_bscan(const int* __restrict__ bsum, int nb,
                        int* __restrict__ boff, int* __restrict__ offsets, int n){
    if (threadIdx.x == 0){
        int run = 0;
        for (int b = 0; b < nb; ++b){ boff[b] = run; run += bsum[b]; }
        offsets[n] = run;
    }
}

__global__ __launch_bounds__(1024) void k_offsets(const int* __restrict__ counts, int n,
                                                  const int* __restrict__ boff,
                                                  int* __restrict__ offsets,
                                                  int* __restrict__ cursor,
                                                  float* __restrict__ dinv){
    __shared__ int sb[1024];
    int i = blockIdx.x * 1024 + threadIdx.x;
    int v = (i < n) ? counts[i] : 0;
    if (i < n) dinv[i] = rsqrtf((float)(v + 1));   // +1 self-loop; deg>=1 always
    sb[threadIdx.x] = v;
    __syncthreads();
    for (int off = 1; off < 1024; off <<= 1){
        int t = (threadIdx.x >= off) ? sb[threadIdx.x - off] : 0;
        __syncthreads();
        sb[threadIdx.x] += t;
        __syncthreads();
    }
    if (i < n){
        int ex = boff[blockIdx.x] + sb[threadIdx.x] - v;
        offsets[i] = ex; cursor[i] = ex;
    }
}

__global__ void k_fill(const int* __restrict__ ei, int E,
                       int* __restrict__ cursor, int* __restrict__ srclist){
    int e = blockIdx.x * 256 + threadIdx.x;
    if (e < E){
        int s = ei[e], d = ei[E + e];
        int pos = atomicAdd(&cursor[d], 1);
        srclist[pos] = s;
    }
}

// ---------------- fp32 GEMM: C[M,Nn] = A[M,K] @ W[K,Nn] ----------------
// BM=128, BN=128, BK=16, 256 threads, 8x8 micro-tile. K%16==0, Nn%128==0.
// SCALE: out row r *= scale[r]. BIAS: + bias[col]. RELU optional.
template<bool SCALE, bool BIAS, bool RELU>
__global__ __launch_bounds__(256) void k_gemm(
        const float* __restrict__ A, const float* __restrict__ W,
        float* __restrict__ C, int M, int K, int Nn,
        const float* __restrict__ scale, const float* __restrict__ bias){
    const int BM = 128, BN = 128, BK = 16;
    __shared__ __align__(16) float As[BK][BM + 4];
    __shared__ __align__(16) float Bs[BK][BN + 4];
    int tid = threadIdx.x;
    int tx = tid & 15, ty = tid >> 4;
    int row0 = blockIdx.x * BM, col0 = blockIdx.y * BN;

    float acc[8][8];
#pragma unroll
    for (int i = 0; i < 8; ++i)
#pragma unroll
        for (int j = 0; j < 8; ++j) acc[i][j] = 0.f;

    for (int kt = 0; kt < K; kt += BK){
        // A tile: 128x16 = 512 float4, transposed into As[k][m]
#pragma unroll
        for (int l = 0; l < 2; ++l){
            int idx = tid + l * 256;
            int r = idx >> 2, c4 = idx & 3;
            int gr = row0 + r;
            float4 v = make_float4(0.f, 0.f, 0.f, 0.f);
            if (gr < M) v = ld4(&A[(size_t)gr * K + kt + c4 * 4]);
            As[c4 * 4 + 0][r] = v.x;
            As[c4 * 4 + 1][r] = v.y;
            As[c4 * 4 + 2][r] = v.z;
            As[c4 * 4 + 3][r] = v.w;
        }
        // B tile: 16x128 = 512 float4
#pragma unroll
        for (int l = 0; l < 2; ++l){
            int idx = tid + l * 256;
            int r = idx >> 5, c4 = idx & 31;
            st4(&Bs[r][c4 * 4], ld4(&W[(size_t)(kt + r) * Nn + col0 + c4 * 4]));
        }
        __syncthreads();
#pragma unroll
        for (int kk = 0; kk < BK; ++kk){
            float4 a0 = ld4(&As[kk][ty * 8]);
            float4 a1 = ld4(&As[kk][ty * 8 + 4]);
            float4 b0 = ld4(&Bs[kk][tx * 8]);
            float4 b1 = ld4(&Bs[kk][tx * 8 + 4]);
            float av[8] = {a0.x, a0.y, a0.z, a0.w, a1.x, a1.y, a1.z, a1.w};
            float bv[8] = {b0.x, b0.y, b0.z, b0.w, b1.x, b1.y, b1.z, b1.w};
#pragma unroll
            for (int i = 0; i < 8; ++i)
#pragma unroll
                for (int j = 0; j < 8; ++j)
                    acc[i][j] = fmaf(av[i], bv[j], acc[i][j]);
        }
        __syncthreads();
    }

    float bq[8] = {0.f,0.f,0.f,0.f,0.f,0.f,0.f,0.f};
    if (BIAS){
        float4 b0 = ld4(&bias[col0 + tx * 8]);
        float4 b1 = ld4(&bias[col0 + tx * 8 + 4]);
        bq[0]=b0.x; bq[1]=b0.y; bq[2]=b0.z; bq[3]=b0.w;
        bq[4]=b1.x; bq[5]=b1.y; bq[6]=b1.z; bq[7]=b1.w;
    }
#pragma unroll
    for (int i = 0; i < 8; ++i){
        int r = row0 + ty * 8 + i;
        if (r < M){
            float s = SCALE ? scale[r] : 1.f;
            float v[8];
#pragma unroll
            for (int j = 0; j < 8; ++j){
                v[j] = acc[i][j] * s + bq[j];
                if (RELU) v[j] = fmaxf(v[j], 0.f);
            }
            st4(&C[(size_t)r * Nn + col0 + tx * 8],     make_float4(v[0], v[1], v[2], v[3]));
            st4(&C[(size_t)r * Nn + col0 + tx * 8 + 4], make_float4(v[4], v[5], v[6], v[7]));
        }
    }
}

// ---------------- CSR aggregation: one wave per node, 256 features ----------------
// out[n] = relu((hw[n] + sum_{s in in-nbrs} hw[s]) * dinv[n] + bias)
// (hw rows already scaled by dinv[row] in the GEMM epilogue)
__global__ __launch_bounds__(256) void k_aggregate(
        const float* __restrict__ hw, const int* __restrict__ offsets,
        const int* __restrict__ srclist, const float* __restrict__ dinv,
        const float* __restrict__ bias, float* __restrict__ out, int n){
    int wid = (blockIdx.x * 256 + threadIdx.x) >> 6;
    int lane = threadIdx.x & 63;
    if (wid >= n) return;
    int f = lane * 4;
    float4 acc = ld4(&hw[(size_t)wid * 256 + f]);   // self loop
    int o0 = offsets[wid], o1 = offsets[wid + 1];
    int e = o0;
    for (; e + 1 < o1; e += 2){
        int s0 = srclist[e], s1 = srclist[e + 1];
        float4 v0 = ld4(&hw[(size_t)s0 * 256 + f]);
        float4 v1 = ld4(&hw[(size_t)s1 * 256 + f]);
        acc.x += v0.x + v1.x; acc.y += v0.y + v1.y;
        acc.z += v0.z + v1.z; acc.w += v0.w + v1.w;
    }
    if (e < o1){
        int s0 = srclist[e];
        float4 v0 = ld4(&hw[(size_t)s0 * 256 + f]);
        acc.x += v0.x; acc.y += v0.y; acc.z += v0.z; acc.w += v0.w;
    }
    float d = dinv[wid];
    float4 bb = ld4(&bias[f]);
    float4 o;
    o.x = fmaxf(acc.x * d + bb.x, 0.f);
    o.y = fmaxf(acc.y * d + bb.y, 0.f);
    o.z = fmaxf(acc.z * d + bb.z, 0.f);
    o.w = fmaxf(acc.w * d + bb.w, 0.f);
    st4(&out[(size_t)wid * 256 + f], o);
}

// ---------------- fused decoder ----------------
// Per block: 64 queries. Build u1 tile (16 k-cols at a time) in LDS from
// gathered A[qs], B[qd] + idiff*Wd1[256] + sp*Wd1[257], relu. Then GEMM vs
// Wd2 (256x128), relu+bd2, dot with Wd3, sigmoid. No u1 materialization.
__global__ __launch_bounds__(256) void k_dec(
        const float* __restrict__ Az, const float* __restrict__ Bz,
        const int* __restrict__ qe, const int* __restrict__ iv, const int* __restrict__ pid,
        const float* __restrict__ Wd1, const float* __restrict__ Wd2,
        const float* __restrict__ bd2, const float* __restrict__ Wd3,
        const float* __restrict__ bd3, float* __restrict__ out, int Q){
    const int BK = 16;
    __shared__ __align__(16) float As[BK][64 + 4];    // u1^T tile
    __shared__ __align__(16) float Bs[BK][128 + 4];   // Wd2 tile
    __shared__ float red[64][17];
    __shared__ int   sQs[64], sQd[64];
    __shared__ float sId[64], sSp[64];

    int tid = threadIdx.x;
    int row0 = blockIdx.x * 64;
    if (tid < 64){
        int r = row0 + tid;
        int qs = 0, qd = 0; float idf = 0.f, sp = 0.f;
        if (r < Q){
            qs = qe[r]; qd = qe[Q + r];
            idf = (float)(iv[qd] - iv[qs]);
            sp = (pid[qs] == pid[qd]) ? 1.f : 0.f;
        }
        sQs[tid] = qs; sQd[tid] = qd; sId[tid] = idf; sSp[tid] = sp;
    }
    __syncthreads();

    int tx = tid & 15, ty = tid >> 4;
    int lr = tid >> 2, lc = tid & 3;          // u1-tile build: row lr, col-group lc
    bool rowok = (row0 + lr < Q);
    int qs = sQs[lr], qd = sQd[lr];
    float idf = sId[lr], sp = sSp[lr];

    float acc[4][8];
#pragma unroll
    for (int i = 0; i < 4; ++i)
#pragma unroll
        for (int j = 0; j < 8; ++j) acc[i][j] = 0.f;

    for (int kt = 0; kt < 256; kt += BK){
        // build u1^T tile: each thread one float4 of one row
        float4 va = make_float4(0.f, 0.f, 0.f, 0.f);
        if (rowok){
            float4 a  = ld4(&Az[(size_t)qs * 256 + kt + lc * 4]);
            float4 b  = ld4(&Bz[(size_t)qd * 256 + kt + lc * 4]);
            float4 wi = ld4(&Wd1[256 * 256 + kt + lc * 4]);
            float4 ws = ld4(&Wd1[257 * 256 + kt + lc * 4]);
            va.x = fmaxf(a.x + b.x + idf * wi.x + sp * ws.x, 0.f);
            va.y = fmaxf(a.y + b.y + idf * wi.y + sp * ws.y, 0.f);
            va.z = fmaxf(a.z + b.z + idf * wi.z + sp * ws.z, 0.f);
            va.w = fmaxf(a.w + b.w + idf * wi.w + sp * ws.w, 0.f);
        }
        As[lc * 4 + 0][lr] = va.x;
        As[lc * 4 + 1][lr] = va.y;
        As[lc * 4 + 2][lr] = va.z;
        As[lc * 4 + 3][lr] = va.w;
        // Wd2 tile 16x128
#pragma unroll
        for (int l = 0; l < 2; ++l){
            int idx = tid + l * 256;
            int r = idx >> 5, c4 = idx & 31;
            st4(&Bs[r][c4 * 4], ld4(&Wd2[(size_t)(kt + r) * 128 + c4 * 4]));
        }
        __syncthreads();
#pragma unroll
        for (int kk = 0; kk < BK; ++kk){
            float4 a  = ld4(&As[kk][ty * 4]);
            float4 b0 = ld4(&Bs[kk][tx * 8]);
            float4 b1 = ld4(&Bs[kk][tx * 8 + 4]);
            float av[4] = {a.x, a.y, a.z, a.w};
            float bv[8] = {b0.x, b0.y, b0.z, b0.w, b1.x, b1.y, b1.z, b1.w};
#pragma unroll
            for (int i = 0; i < 4; ++i)
#pragma unroll
                for (int j = 0; j < 8; ++j)
                    acc[i][j] = fmaf(av[i], bv[j], acc[i][j]);
        }
        __syncthreads();
    }

    float4 c0 = ld4(&bd2[tx * 8]), c1 = ld4(&bd2[tx * 8 + 4]);
    float4 w0 = ld4(&Wd3[tx * 8]), w1 = ld4(&Wd3[tx * 8 + 4]);
    float cb[8] = {c0.x, c0.y, c0.z, c0.w, c1.x, c1.y, c1.z, c1.w};
    float wv[8] = {w0.x, w0.y, w0.z, w0.w, w1.x, w1.y, w1.z, w1.w};
#pragma unroll
    for (int i = 0; i < 4; ++i){
        float p = 0.f;
#pragma unroll
        for (int j = 0; j < 8; ++j)
            p += fmaxf(acc[i][j] + cb[j], 0.f) * wv[j];
        red[ty * 4 + i][tx] = p;
    }
    __syncthreads();
    if (tid < 64){
        float s = 0.f;
#pragma unroll
        for (int t = 0; t < 16; ++t) s += red[tid][t];
        int r = row0 + tid;
        if (r < Q) out[r] = 1.f / (1.f + expf(-(s + bd3[0])));
    }
}

// ---------------- launch ----------------
extern "C" void kernel_launch(void* const* d_in, const int* in_sizes, int n_in,
                              void* d_out, int out_size, void* d_ws, size_t ws_size,
                              hipStream_t stream){
    const float* x   = (const float*)d_in[0];
    const int*   ei  = (const int*)  d_in[1];
    const int*   qe  = (const int*)  d_in[2];
    const int*   iv  = (const int*)  d_in[3];
    const int*   pid = (const int*)  d_in[4];
    const float* W1  = (const float*)d_in[5];
    const float* b1  = (const float*)d_in[6];
    const float* W2  = (const float*)d_in[7];
    const float* b2  = (const float*)d_in[8];
    const float* Wfc = (const float*)d_in[9];
    const float* bfc = (const float*)d_in[10];
    const float* Wd1 = (const float*)d_in[11];
    const float* bd1 = (const float*)d_in[12];
    const float* Wd2 = (const float*)d_in[13];
    const float* bd2 = (const float*)d_in[14];
    const float* Wd3 = (const float*)d_in[15];
    const float* bd3 = (const float*)d_in[16];
    float* out = (float*)d_out;

    const int N = in_sizes[3];
    const int E = in_sizes[1] / 2;
    const int Q = in_sizes[2] / 2;
    const int F = in_sizes[0] / N;   // 128

    char* p = (char*)d_ws;
    auto alloc = [&](size_t bytes) -> char* {
        char* r = p; p += (bytes + 255) & ~(size_t)255; return r;
    };
    int*   counts  = (int*)  alloc((size_t)N * 4);
    int*   offsets = (int*)  alloc((size_t)(N + 1) * 4);
    int*   cursor  = (int*)  alloc((size_t)(N + 1) * 4);
    int*   srclist = (int*)  alloc((size_t)E * 4);
    float* dinv    = (float*)alloc((size_t)N * 4);
    int*   bsum    = (int*)  alloc(1024 * 4);
    int*   boff    = (int*)  alloc(1024 * 4);
    float* bufA    = (float*)alloc((size_t)N * 256 * 4);  // hw / decoder A
    float* bufC    = (float*)alloc((size_t)N * 256 * 4);  // h  / decoder B
    float* z       = (float*)alloc((size_t)N * 128 * 4);

    const int nb = (N + 1023) / 1024;

    hipMemsetAsync(counts, 0, (size_t)N * 4, stream);
    k_count   <<<dim3((E + 255) / 256), dim3(256),  0, stream>>>(ei, E, counts);
    k_blocksum<<<dim3(nb),              dim3(1024), 0, stream>>>(counts, N, bsum);
    k_bscan   <<<dim3(1),               dim3(64),   0, stream>>>(bsum, nb, boff, offsets, N);
    k_offsets <<<dim3(nb),              dim3(1024), 0, stream>>>(counts, N, boff, offsets, cursor, dinv);
    k_fill    <<<dim3((E + 255) / 256), dim3(256),  0, stream>>>(ei, E, cursor, srclist);

    dim3 blk(256);
    dim3 g256((N + 127) / 128, 2);   // Nn = 256
    dim3 g128((N + 127) / 128, 1);   // Nn = 128
    dim3 gagg((N * 64 + 255) / 256);

    // conv1
    k_gemm<true,  false, false><<<g256, blk, 0, stream>>>(x,    W1,  bufA, N, F,   256, dinv, nullptr);
    k_aggregate<<<gagg, blk, 0, stream>>>(bufA, offsets, srclist, dinv, b1, bufC, N);
    // conv2
    k_gemm<true,  false, false><<<g256, blk, 0, stream>>>(bufC, W2,  bufA, N, 256, 256, dinv, nullptr);
    k_aggregate<<<gagg, blk, 0, stream>>>(bufA, offsets, srclist, dinv, b2, bufC, N);
    // z = h2 @ Wfc + bfc
    k_gemm<false, true,  false><<<g128, blk, 0, stream>>>(bufC, Wfc, z,    N, 256, 128, nullptr, bfc);
    // decoder stage-1 over nodes: A = z@Wd1[0:128]+bd1 ; B = z@Wd1[128:256]
    k_gemm<false, true,  false><<<g256, blk, 0, stream>>>(z, Wd1,             bufA, N, 128, 256, nullptr, bd1);
    k_gemm<false, false, false><<<g256, blk, 0, stream>>>(z, Wd1 + 128 * 256, bufC, N, 128, 256, nullptr, nullptr);
    // fused decoder over all queries
    k_dec<<<dim3((Q + 63) / 64), blk, 0, stream>>>(bufA, bufC, qe, iv, pid,
                                                   Wd1, Wd2, bd2, Wd3, bd3, out, Q);
}

// Round 3
// 1680.887 us; speedup vs baseline: 1.0551x; 1.0551x over previous
//
#include <hip/hip_runtime.h>
#include <math.h>

// NextIntegerLinkPredictor, round 3.
// Key changes vs round 2:
//  - All dense GEMMs on MFMA (bf16 hi/lo split x3 => ~fp32 precision).
//  - Decoder gathers z directly (51 MB, L3-resident) instead of 204 MB A/B
//    tables; both decoder stages fused in one MFMA kernel; rank-1 idiff/sp
//    terms added exactly in fp32.
//  - conv1 aggregates FIRST at width 128 (A-hat commutes with W multiply).

typedef __attribute__((ext_vector_type(8))) short short8;
typedef __attribute__((ext_vector_type(4))) float f32x4;

__device__ __forceinline__ float4 ld4(const float* p){ return *reinterpret_cast<const float4*>(p); }
__device__ __forceinline__ void st4(float* p, float4 v){ *reinterpret_cast<float4*>(p) = v; }
__device__ __forceinline__ unsigned short f2bf(float f){
    union{float f; unsigned u;} v; v.f = f;
    unsigned r = (v.u + 0x7FFFu + ((v.u >> 16) & 1u)) >> 16;
    return (unsigned short)r;
}
__device__ __forceinline__ float bf2f(unsigned short b){
    union{unsigned u; float f;} v; v.u = ((unsigned)b) << 16; return v.f;
}

// ---------------- CSR build ----------------
__global__ void k_count(const int* __restrict__ ei, int E, int* __restrict__ counts){
    int e = blockIdx.x * 256 + threadIdx.x;
    if (e < E) atomicAdd(&counts[ei[E + e]], 1);
}

__global__ __launch_bounds__(1024) void k_blocksum(const int* __restrict__ counts, int n,
                                                   int* __restrict__ bsum){
    __shared__ int sb[1024];
    int i = blockIdx.x * 1024 + threadIdx.x;
    sb[threadIdx.x] = (i < n) ? counts[i] : 0;
    __syncthreads();
    for (int off = 512; off > 0; off >>= 1){
        if (threadIdx.x < off) sb[threadIdx.x] += sb[threadIdx.x + off];
        __syncthreads();
    }
    if (threadIdx.x == 0) bsum[blockIdx.x] = sb[0];
}

__global__ void k_bscan(const int* __restrict__ bsum, int nb,
                        int* __restrict__ boff, int* __restrict__ offsets, int n){
    if (threadIdx.x == 0){
        int run = 0;
        for (int b = 0; b < nb; ++b){ boff[b] = run; run += bsum[b]; }
        offsets[n] = run;
    }
}

__global__ __launch_bounds__(1024) void k_offsets(const int* __restrict__ counts, int n,
                                                  const int* __restrict__ boff,
                                                  int* __restrict__ offsets,
                                                  int* __restrict__ cursor,
                                                  float* __restrict__ dinv){
    __shared__ int sb[1024];
    int i = blockIdx.x * 1024 + threadIdx.x;
    int v = (i < n) ? counts[i] : 0;
    if (i < n) dinv[i] = rsqrtf((float)(v + 1));   // +1 self-loop
    sb[threadIdx.x] = v;
    __syncthreads();
    for (int off = 1; off < 1024; off <<= 1){
        int t = (threadIdx.x >= off) ? sb[threadIdx.x - off] : 0;
        __syncthreads();
        sb[threadIdx.x] += t;
        __syncthreads();
    }
    if (i < n){
        int ex = boff[blockIdx.x] + sb[threadIdx.x] - v;
        offsets[i] = ex; cursor[i] = ex;
    }
}

__global__ void k_fill(const int* __restrict__ ei, int E,
                       int* __restrict__ cursor, int* __restrict__ srclist){
    int e = blockIdx.x * 256 + threadIdx.x;
    if (e < E){
        int s = ei[e], d = ei[E + e];
        int pos = atomicAdd(&cursor[d], 1);
        srclist[pos] = s;
    }
}

// ---------------- weight split: W[K][Nn] fp32 -> Wt hi/lo bf16 [Nn][K] ----------------
__global__ void k_split_w(const float* __restrict__ W, unsigned short* __restrict__ hi,
                          unsigned short* __restrict__ lo, int K, int Nn){
    int id = blockIdx.x * 256 + threadIdx.x;
    if (id >= K * Nn) return;
    int n = id / K, k = id - n * K;
    float v = W[(size_t)k * Nn + n];
    unsigned short h = f2bf(v);
    hi[id] = h;
    lo[id] = f2bf(v - bf2f(h));
}

// ---------------- xs = x * dinv[row], width 128 ----------------
__global__ void k_scalerows(const float* __restrict__ x, const float* __restrict__ dinv,
                            float* __restrict__ xs, int total4){
    int id = blockIdx.x * 256 + threadIdx.x;
    if (id >= total4) return;
    int node = id >> 5;              // 128 floats/row = 32 float4
    float d = dinv[node];
    float4 v = ld4(&x[(size_t)id * 4]);
    st4(&xs[(size_t)id * 4], make_float4(v.x*d, v.y*d, v.z*d, v.w*d));
}

// ---------------- CSR aggregate, width 128 (float2/lane) ----------------
__global__ __launch_bounds__(256) void k_agg2(const float* __restrict__ in,
        const int* __restrict__ offsets, const int* __restrict__ srclist,
        const float* __restrict__ dinv, float* __restrict__ out, int n){
    int wid = (blockIdx.x * 256 + threadIdx.x) >> 6;
    int lane = threadIdx.x & 63;
    if (wid >= n) return;
    int f = lane * 2;
    float2 acc = *reinterpret_cast<const float2*>(&in[(size_t)wid * 128 + f]);
    int o0 = offsets[wid], o1 = offsets[wid + 1];
    int e = o0;
    for (; e + 3 < o1; e += 4){
        int s0 = srclist[e], s1 = srclist[e+1], s2 = srclist[e+2], s3 = srclist[e+3];
        float2 v0 = *reinterpret_cast<const float2*>(&in[(size_t)s0 * 128 + f]);
        float2 v1 = *reinterpret_cast<const float2*>(&in[(size_t)s1 * 128 + f]);
        float2 v2 = *reinterpret_cast<const float2*>(&in[(size_t)s2 * 128 + f]);
        float2 v3 = *reinterpret_cast<const float2*>(&in[(size_t)s3 * 128 + f]);
        acc.x += (v0.x + v1.x) + (v2.x + v3.x);
        acc.y += (v0.y + v1.y) + (v2.y + v3.y);
    }
    for (; e < o1; ++e){
        int s0 = srclist[e];
        float2 v0 = *reinterpret_cast<const float2*>(&in[(size_t)s0 * 128 + f]);
        acc.x += v0.x; acc.y += v0.y;
    }
    float d = dinv[wid];
    float2 o; o.x = acc.x * d; o.y = acc.y * d;
    *reinterpret_cast<float2*>(&out[(size_t)wid * 128 + f]) = o;
}

// ---------------- CSR aggregate, width 256 (float4/lane) ----------------
__global__ __launch_bounds__(256) void k_agg4(const float* __restrict__ in,
        const int* __restrict__ offsets, const int* __restrict__ srclist,
        const float* __restrict__ dinv, float* __restrict__ out, int n){
    int wid = (blockIdx.x * 256 + threadIdx.x) >> 6;
    int lane = threadIdx.x & 63;
    if (wid >= n) return;
    int f = lane * 4;
    float4 acc = ld4(&in[(size_t)wid * 256 + f]);
    int o0 = offsets[wid], o1 = offsets[wid + 1];
    int e = o0;
    for (; e + 3 < o1; e += 4){
        int s0 = srclist[e], s1 = srclist[e+1], s2 = srclist[e+2], s3 = srclist[e+3];
        float4 v0 = ld4(&in[(size_t)s0 * 256 + f]);
        float4 v1 = ld4(&in[(size_t)s1 * 256 + f]);
        float4 v2 = ld4(&in[(size_t)s2 * 256 + f]);
        float4 v3 = ld4(&in[(size_t)s3 * 256 + f]);
        acc.x += (v0.x + v1.x) + (v2.x + v3.x);
        acc.y += (v0.y + v1.y) + (v2.y + v3.y);
        acc.z += (v0.z + v1.z) + (v2.z + v3.z);
        acc.w += (v0.w + v1.w) + (v2.w + v3.w);
    }
    for (; e < o1; ++e){
        int s0 = srclist[e];
        float4 v0 = ld4(&in[(size_t)s0 * 256 + f]);
        acc.x += v0.x; acc.y += v0.y; acc.z += v0.z; acc.w += v0.w;
    }
    float d = dinv[wid];
    float4 o;
    o.x = acc.x * d; o.y = acc.y * d; o.z = acc.z * d; o.w = acc.w * d;
    st4(&out[(size_t)wid * 256 + f], o);
}

// ---------------- MFMA bf16x3 GEMM: C[M,Nn] = A[M,K] @ W + bias ----------------
// A fp32 row-major. W pre-split bf16 hi/lo in [Nn][K] layout.
// BM=128, BN=128, BK=32, 256 threads = 4 waves in 2x2; 16x16x32 MFMA.
template<bool RELU, bool POSTSCALE>
__global__ __launch_bounds__(256) void k_mgemm(
        const float* __restrict__ A, const unsigned short* __restrict__ Bh,
        const unsigned short* __restrict__ Bl, const float* __restrict__ bias,
        const float* __restrict__ pscale, float* __restrict__ C,
        int M, int K, int Nn){
    __shared__ unsigned short As_h[128][40], As_l[128][40];   // pad 32->40 (2-way banks)
    __shared__ unsigned short Bs_h[128][40], Bs_l[128][40];
    int tid = threadIdx.x;
    int l = tid & 63, w = tid >> 6;
    int wr = w >> 1, wc = w & 1;
    int row0 = blockIdx.x * 128, col0 = blockIdx.y * 128;
    int lr = l & 15, lg = l >> 4, lk = lg * 8;

    f32x4 acc[4][4] = {};

    for (int kt = 0; kt < K; kt += 32){
        // stage A (fp32 -> split bf16)
#pragma unroll
        for (int lp = 0; lp < 4; ++lp){
            int idx = tid + lp * 256;
            int r = idx >> 3, c4 = idx & 7;
            float4 v = make_float4(0.f, 0.f, 0.f, 0.f);
            if (row0 + r < M) v = ld4(&A[(size_t)(row0 + r) * K + kt + c4 * 4]);
            unsigned short h0 = f2bf(v.x), h1 = f2bf(v.y), h2 = f2bf(v.z), h3 = f2bf(v.w);
            unsigned short e0 = f2bf(v.x - bf2f(h0)), e1 = f2bf(v.y - bf2f(h1));
            unsigned short e2 = f2bf(v.z - bf2f(h2)), e3 = f2bf(v.w - bf2f(h3));
            *reinterpret_cast<uint2*>(&As_h[r][c4 * 4]) =
                make_uint2((unsigned)h0 | ((unsigned)h1 << 16), (unsigned)h2 | ((unsigned)h3 << 16));
            *reinterpret_cast<uint2*>(&As_l[r][c4 * 4]) =
                make_uint2((unsigned)e0 | ((unsigned)e1 << 16), (unsigned)e2 | ((unsigned)e3 << 16));
        }
        // stage B (pre-split, copy 16B chunks)
#pragma unroll
        for (int lp = 0; lp < 2; ++lp){
            int idx = tid + lp * 256;
            int r = idx >> 2, c8 = idx & 3;
            size_t go = (size_t)(col0 + r) * K + kt + c8 * 8;
            *reinterpret_cast<uint4*>(&Bs_h[r][c8 * 8]) = *reinterpret_cast<const uint4*>(&Bh[go]);
            *reinterpret_cast<uint4*>(&Bs_l[r][c8 * 8]) = *reinterpret_cast<const uint4*>(&Bl[go]);
        }
        __syncthreads();

        short8 ah[4], al[4], bh[4], bl[4];
#pragma unroll
        for (int mi = 0; mi < 4; ++mi){
            ah[mi] = *reinterpret_cast<const short8*>(&As_h[wr * 64 + mi * 16 + lr][lk]);
            al[mi] = *reinterpret_cast<const short8*>(&As_l[wr * 64 + mi * 16 + lr][lk]);
        }
#pragma unroll
        for (int ni = 0; ni < 4; ++ni){
            bh[ni] = *reinterpret_cast<const short8*>(&Bs_h[wc * 64 + ni * 16 + lr][lk]);
            bl[ni] = *reinterpret_cast<const short8*>(&Bs_l[wc * 64 + ni * 16 + lr][lk]);
        }
#pragma unroll
        for (int mi = 0; mi < 4; ++mi)
#pragma unroll
            for (int ni = 0; ni < 4; ++ni)
                acc[mi][ni] = __builtin_amdgcn_mfma_f32_16x16x32_bf16(ah[mi], bh[ni], acc[mi][ni], 0, 0, 0);
#pragma unroll
        for (int mi = 0; mi < 4; ++mi)
#pragma unroll
            for (int ni = 0; ni < 4; ++ni)
                acc[mi][ni] = __builtin_amdgcn_mfma_f32_16x16x32_bf16(ah[mi], bl[ni], acc[mi][ni], 0, 0, 0);
#pragma unroll
        for (int mi = 0; mi < 4; ++mi)
#pragma unroll
            for (int ni = 0; ni < 4; ++ni)
                acc[mi][ni] = __builtin_amdgcn_mfma_f32_16x16x32_bf16(al[mi], bh[ni], acc[mi][ni], 0, 0, 0);
        __syncthreads();
    }

    // epilogue: C/D layout col = lane&15, row = (lane>>4)*4 + reg
#pragma unroll
    for (int ni = 0; ni < 4; ++ni){
        int col = col0 + wc * 64 + ni * 16 + lr;
        float bv = bias[col];
#pragma unroll
        for (int mi = 0; mi < 4; ++mi){
#pragma unroll
            for (int rr = 0; rr < 4; ++rr){
                int grow = row0 + wr * 64 + mi * 16 + lg * 4 + rr;
                if (grow < M){
                    float v = acc[mi][ni][rr] + bv;
                    if (RELU) v = fmaxf(v, 0.f);
                    if (POSTSCALE) v *= pscale[grow];
                    C[(size_t)grow * Nn + col] = v;
                }
            }
        }
    }
}

// ---------------- fused decoder, MFMA bf16x3 ----------------
// 32 queries/block, 256 threads = 4 waves (wave w owns 64-col slab in stage 1,
// 32-col slab in stage 2).
// stage1: u1[32][256] = relu(zc @ Wd1[0:256] + bd1 + idf*wi + sp*ws)
// stage2: u2 = relu(u1 @ Wd2 + bd2); out = sigmoid(u2 . Wd3 + bd3)
__global__ __launch_bounds__(256) void k_dec(
        const float* __restrict__ z, const int* __restrict__ qe,
        const int* __restrict__ iv, const int* __restrict__ pid,
        const unsigned short* __restrict__ W1h, const unsigned short* __restrict__ W1l,
        const float* __restrict__ Wd1, const float* __restrict__ bd1,
        const unsigned short* __restrict__ W2h, const unsigned short* __restrict__ W2l,
        const float* __restrict__ bd2, const float* __restrict__ Wd3,
        const float* __restrict__ bd3, float* __restrict__ out, int Q){
    __shared__ unsigned short As_h[32][40], As_l[32][40];
    __shared__ unsigned short U_h[32][264], U_l[32][264];
    __shared__ float red[32][65];
    __shared__ int   sQs[32], sQd[32];
    __shared__ float sIdf[32], sSp[32];

    int tid = threadIdx.x;
    int q0 = blockIdx.x * 32;
    if (tid < 32){
        int q = q0 + tid;
        int qs = 0, qd = 0; float idf = 0.f, sp = 0.f;
        if (q < Q){
            qs = qe[q]; qd = qe[Q + q];
            idf = (float)(iv[qd] - iv[qs]);
            sp = (pid[qs] == pid[qd]) ? 1.f : 0.f;
        }
        sQs[tid] = qs; sQd[tid] = qd; sIdf[tid] = idf; sSp[tid] = sp;
    }
    __syncthreads();

    int l = tid & 63, wc = tid >> 6;
    int lr = l & 15, lg = l >> 4, lk = lg * 8;

    // ---- stage 1 ----
    f32x4 acc1[2][4] = {};
    for (int kt = 0; kt < 256; kt += 32){
        {   // gather zc tile 32 rows x 32 cols (rows from z[qs] then z[qd])
            int r = tid >> 3, c4 = tid & 7;
            int srow = (kt < 128) ? sQs[r] : sQd[r];
            int col = (kt & 127) + c4 * 4;
            float4 v = ld4(&z[(size_t)srow * 128 + col]);
            unsigned short h0 = f2bf(v.x), h1 = f2bf(v.y), h2 = f2bf(v.z), h3 = f2bf(v.w);
            unsigned short e0 = f2bf(v.x - bf2f(h0)), e1 = f2bf(v.y - bf2f(h1));
            unsigned short e2 = f2bf(v.z - bf2f(h2)), e3 = f2bf(v.w - bf2f(h3));
            *reinterpret_cast<uint2*>(&As_h[r][c4 * 4]) =
                make_uint2((unsigned)h0 | ((unsigned)h1 << 16), (unsigned)h2 | ((unsigned)h3 << 16));
            *reinterpret_cast<uint2*>(&As_l[r][c4 * 4]) =
                make_uint2((unsigned)e0 | ((unsigned)e1 << 16), (unsigned)e2 | ((unsigned)e3 << 16));
        }
        __syncthreads();

        short8 ah[2], al[2], bh[4], bl[4];
#pragma unroll
        for (int mi = 0; mi < 2; ++mi){
            ah[mi] = *reinterpret_cast<const short8*>(&As_h[mi * 16 + lr][lk]);
            al[mi] = *reinterpret_cast<const short8*>(&As_l[mi * 16 + lr][lk]);
        }
#pragma unroll
        for (int ni = 0; ni < 4; ++ni){
            size_t go = (size_t)(wc * 64 + ni * 16 + lr) * 256 + kt + lk;
            bh[ni] = *reinterpret_cast<const short8*>(&W1h[go]);
            bl[ni] = *reinterpret_cast<const short8*>(&W1l[go]);
        }
#pragma unroll
        for (int mi = 0; mi < 2; ++mi)
#pragma unroll
            for (int ni = 0; ni < 4; ++ni)
                acc1[mi][ni] = __builtin_amdgcn_mfma_f32_16x16x32_bf16(ah[mi], bh[ni], acc1[mi][ni], 0, 0, 0);
#pragma unroll
        for (int mi = 0; mi < 2; ++mi)
#pragma unroll
            for (int ni = 0; ni < 4; ++ni)
                acc1[mi][ni] = __builtin_amdgcn_mfma_f32_16x16x32_bf16(ah[mi], bl[ni], acc1[mi][ni], 0, 0, 0);
#pragma unroll
        for (int mi = 0; mi < 2; ++mi)
#pragma unroll
            for (int ni = 0; ni < 4; ++ni)
                acc1[mi][ni] = __builtin_amdgcn_mfma_f32_16x16x32_bf16(al[mi], bh[ni], acc1[mi][ni], 0, 0, 0);
        __syncthreads();
    }

    // u1 epilogue: + bd1 + idf*wi + sp*ws (exact fp32), relu, split-bf16 into U
#pragma unroll
    for (int ni = 0; ni < 4; ++ni){
        int c = wc * 64 + ni * 16 + lr;
        float bv = bd1[c];
        float wiv = Wd1[256 * 256 + c];
        float wsv = Wd1[257 * 256 + c];
#pragma unroll
        for (int mi = 0; mi < 2; ++mi){
#pragma unroll
            for (int rr = 0; rr < 4; ++rr){
                int r = mi * 16 + lg * 4 + rr;
                float u = acc1[mi][ni][rr] + bv + sIdf[r] * wiv + sSp[r] * wsv;
                u = fmaxf(u, 0.f);
                unsigned short h = f2bf(u);
                U_h[r][c] = h;
                U_l[r][c] = f2bf(u - bf2f(h));
            }
        }
    }
    __syncthreads();

    // ---- stage 2 ----
    f32x4 acc2[2][2] = {};
    for (int kt = 0; kt < 256; kt += 32){
        short8 ah[2], al[2], bh[2], bl[2];
#pragma unroll
        for (int mi = 0; mi < 2; ++mi){
            ah[mi] = *reinterpret_cast<const short8*>(&U_h[mi * 16 + lr][kt + lk]);
            al[mi] = *reinterpret_cast<const short8*>(&U_l[mi * 16 + lr][kt + lk]);
        }
#pragma unroll
        for (int ni = 0; ni < 2; ++ni){
            size_t go = (size_t)(wc * 32 + ni * 16 + lr) * 256 + kt + lk;
            bh[ni] = *reinterpret_cast<const short8*>(&W2h[go]);
            bl[ni] = *reinterpret_cast<const short8*>(&W2l[go]);
        }
#pragma unroll
        for (int mi = 0; mi < 2; ++mi)
#pragma unroll
            for (int ni = 0; ni < 2; ++ni)
                acc2[mi][ni] = __builtin_amdgcn_mfma_f32_16x16x32_bf16(ah[mi], bh[ni], acc2[mi][ni], 0, 0, 0);
#pragma unroll
        for (int mi = 0; mi < 2; ++mi)
#pragma unroll
            for (int ni = 0; ni < 2; ++ni)
                acc2[mi][ni] = __builtin_amdgcn_mfma_f32_16x16x32_bf16(ah[mi], bl[ni], acc2[mi][ni], 0, 0, 0);
#pragma unroll
        for (int mi = 0; mi < 2; ++mi)
#pragma unroll
            for (int ni = 0; ni < 2; ++ni)
                acc2[mi][ni] = __builtin_amdgcn_mfma_f32_16x16x32_bf16(al[mi], bh[ni], acc2[mi][ni], 0, 0, 0);
    }

    // epilogue: relu(+bd2), dot with Wd3, reduce, sigmoid
    float psum[2][4] = {};
#pragma unroll
    for (int ni = 0; ni < 2; ++ni){
        int c = wc * 32 + ni * 16 + lr;
        float b2v = bd2[c];
        float w3v = Wd3[c];
#pragma unroll
        for (int mi = 0; mi < 2; ++mi)
#pragma unroll
            for (int rr = 0; rr < 4; ++rr)
                psum[mi][rr] += fmaxf(acc2[mi][ni][rr] + b2v, 0.f) * w3v;
    }
#pragma unroll
    for (int mi = 0; mi < 2; ++mi)
#pragma unroll
        for (int rr = 0; rr < 4; ++rr)
            red[mi * 16 + lg * 4 + rr][wc * 16 + lr] = psum[mi][rr];
    __syncthreads();
    if (tid < 32){
        float s = 0.f;
#pragma unroll
        for (int c2 = 0; c2 < 64; ++c2) s += red[tid][c2];
        int q = q0 + tid;
        if (q < Q) out[q] = 1.f / (1.f + expf(-(s + bd3[0])));
    }
}

// ---------------- launch ----------------
extern "C" void kernel_launch(void* const* d_in, const int* in_sizes, int n_in,
                              void* d_out, int out_size, void* d_ws, size_t ws_size,
                              hipStream_t stream){
    const float* x   = (const float*)d_in[0];
    const int*   ei  = (const int*)  d_in[1];
    const int*   qe  = (const int*)  d_in[2];
    const int*   iv  = (const int*)  d_in[3];
    const int*   pid = (const int*)  d_in[4];
    const float* W1  = (const float*)d_in[5];
    const float* b1  = (const float*)d_in[6];
    const float* W2  = (const float*)d_in[7];
    const float* b2  = (const float*)d_in[8];
    const float* Wfc = (const float*)d_in[9];
    const float* bfc = (const float*)d_in[10];
    const float* Wd1 = (const float*)d_in[11];
    const float* bd1 = (const float*)d_in[12];
    const float* Wd2 = (const float*)d_in[13];
    const float* bd2 = (const float*)d_in[14];
    const float* Wd3 = (const float*)d_in[15];
    const float* bd3 = (const float*)d_in[16];
    float* out = (float*)d_out;

    const int N = in_sizes[3];
    const int E = in_sizes[1] / 2;
    const int Q = in_sizes[2] / 2;

    char* p = (char*)d_ws;
    auto alloc = [&](size_t bytes) -> char* {
        char* r = p; p += (bytes + 255) & ~(size_t)255; return r;
    };
    int*   counts  = (int*)  alloc((size_t)N * 4);
    int*   offsets = (int*)  alloc((size_t)(N + 1) * 4);
    int*   cursor  = (int*)  alloc((size_t)(N + 1) * 4);
    int*   srclist = (int*)  alloc((size_t)E * 4);
    float* dinv    = (float*)alloc((size_t)N * 4);
    int*   bsum    = (int*)  alloc(1024 * 4);
    int*   boff    = (int*)  alloc(1024 * 4);
    unsigned short* w1h  = (unsigned short*)alloc(256 * 128 * 2);
    unsigned short* w1l  = (unsigned short*)alloc(256 * 128 * 2);
    unsigned short* w2h  = (unsigned short*)alloc(256 * 256 * 2);
    unsigned short* w2l  = (unsigned short*)alloc(256 * 256 * 2);
    unsigned short* wfh  = (unsigned short*)alloc(128 * 256 * 2);
    unsigned short* wfl  = (unsigned short*)alloc(128 * 256 * 2);
    unsigned short* wd1h = (unsigned short*)alloc(256 * 256 * 2);
    unsigned short* wd1l = (unsigned short*)alloc(256 * 256 * 2);
    unsigned short* wd2h = (unsigned short*)alloc(128 * 256 * 2);
    unsigned short* wd2l = (unsigned short*)alloc(128 * 256 * 2);
    float* P1 = (float*)alloc((size_t)N * 256 * 4);   // h1s -> h2
    float* P2 = (float*)alloc((size_t)N * 256 * 4);   // xs+ag1 -> ag2 -> z

    float* xs  = P2;                       // [N,128]
    float* ag1 = P2 + (size_t)N * 128;     // [N,128]
    float* h1s = P1;                       // [N,256]
    float* ag2 = P2;                       // [N,256] (xs/ag1 dead)
    float* h2  = P1;                       // [N,256] (h1s dead)
    float* z   = P2;                       // [N,128] (ag2 dead)

    const int nb = (N + 1023) / 1024;
    dim3 blk(256);

    hipMemsetAsync(counts, 0, (size_t)N * 4, stream);
    k_count   <<<dim3((E + 255) / 256), blk,        0, stream>>>(ei, E, counts);
    k_blocksum<<<dim3(nb),              dim3(1024), 0, stream>>>(counts, N, bsum);
    k_bscan   <<<dim3(1),               dim3(64),   0, stream>>>(bsum, nb, boff, offsets, N);
    k_offsets <<<dim3(nb),              dim3(1024), 0, stream>>>(counts, N, boff, offsets, cursor, dinv);
    k_fill    <<<dim3((E + 255) / 256), blk,        0, stream>>>(ei, E, cursor, srclist);

    // weight splits (transposed to [Nn][K], bf16 hi/lo)
    k_split_w<<<dim3(128), blk, 0, stream>>>(W1,  w1h,  w1l,  128, 256);
    k_split_w<<<dim3(256), blk, 0, stream>>>(W2,  w2h,  w2l,  256, 256);
    k_split_w<<<dim3(128), blk, 0, stream>>>(Wfc, wfh,  wfl,  256, 128);
    k_split_w<<<dim3(256), blk, 0, stream>>>(Wd1, wd1h, wd1l, 256, 256);  // rows 0:256
    k_split_w<<<dim3(128), blk, 0, stream>>>(Wd2, wd2h, wd2l, 256, 128);

    // encoder
    k_scalerows<<<dim3((N * 32 + 255) / 256), blk, 0, stream>>>(x, dinv, xs, N * 32);
    k_agg2<<<dim3(N / 4), blk, 0, stream>>>(xs, offsets, srclist, dinv, ag1, N);
    k_mgemm<true,  true ><<<dim3((N + 127) / 128, 2), blk, 0, stream>>>(ag1, w1h, w1l, b1, dinv, h1s, N, 128, 256);
    k_agg4<<<dim3(N / 4), blk, 0, stream>>>(h1s, offsets, srclist, dinv, ag2, N);
    k_mgemm<true,  false><<<dim3((N + 127) / 128, 2), blk, 0, stream>>>(ag2, w2h, w2l, b2, nullptr, h2, N, 256, 256);
    k_mgemm<false, false><<<dim3((N + 127) / 128, 1), blk, 0, stream>>>(h2, wfh, wfl, bfc, nullptr, z, N, 256, 128);

    // fused decoder
    k_dec<<<dim3((Q + 31) / 32), blk, 0, stream>>>(z, qe, iv, pid,
                                                   wd1h, wd1l, Wd1, bd1,
                                                   wd2h, wd2l, bd2, Wd3, bd3, out, Q);
}

// Round 5
// 1219.764 us; speedup vs baseline: 1.4540x; 1.3780x over previous
//
#include <hip/hip_runtime.h>
#include <math.h>

// NextIntegerLinkPredictor, round 5 (= round-4 kernel, resubmitted after infra
// failure; no counter evidence against it).
// vs round 3: k_dec restructured — 64 queries/block, 512 threads (8 waves),
// full-K A-panel staged+split into LDS once (reused for U), barrier-free
// K-loops, fragment-major packed decoder weights (coalesced 1KB loads).

typedef __attribute__((ext_vector_type(8))) short short8;
typedef __attribute__((ext_vector_type(4))) float f32x4;

__device__ __forceinline__ float4 ld4(const float* p){ return *reinterpret_cast<const float4*>(p); }
__device__ __forceinline__ void st4(float* p, float4 v){ *reinterpret_cast<float4*>(p) = v; }
__device__ __forceinline__ unsigned short f2bf(float f){
    union{float f; unsigned u;} v; v.f = f;
    unsigned r = (v.u + 0x7FFFu + ((v.u >> 16) & 1u)) >> 16;
    return (unsigned short)r;
}
__device__ __forceinline__ float bf2f(unsigned short b){
    union{unsigned u; float f;} v; v.u = ((unsigned)b) << 16; return v.f;
}

// ---------------- CSR build ----------------
__global__ void k_count(const int* __restrict__ ei, int E, int* __restrict__ counts){
    int e = blockIdx.x * 256 + threadIdx.x;
    if (e < E) atomicAdd(&counts[ei[E + e]], 1);
}

__global__ __launch_bounds__(1024) void k_blocksum(const int* __restrict__ counts, int n,
                                                   int* __restrict__ bsum){
    __shared__ int sb[1024];
    int i = blockIdx.x * 1024 + threadIdx.x;
    sb[threadIdx.x] = (i < n) ? counts[i] : 0;
    __syncthreads();
    for (int off = 512; off > 0; off >>= 1){
        if (threadIdx.x < off) sb[threadIdx.x] += sb[threadIdx.x + off];
        __syncthreads();
    }
    if (threadIdx.x == 0) bsum[blockIdx.x] = sb[0];
}

__global__ void k_bscan(const int* __restrict__ bsum, int nb,
                        int* __restrict__ boff, int* __restrict__ offsets, int n){
    if (threadIdx.x == 0){
        int run = 0;
        for (int b = 0; b < nb; ++b){ boff[b] = run; run += bsum[b]; }
        offsets[n] = run;
    }
}

__global__ __launch_bounds__(1024) void k_offsets(const int* __restrict__ counts, int n,
                                                  const int* __restrict__ boff,
                                                  int* __restrict__ offsets,
                                                  int* __restrict__ cursor,
                                                  float* __restrict__ dinv){
    __shared__ int sb[1024];
    int i = blockIdx.x * 1024 + threadIdx.x;
    int v = (i < n) ? counts[i] : 0;
    if (i < n) dinv[i] = rsqrtf((float)(v + 1));   // +1 self-loop
    sb[threadIdx.x] = v;
    __syncthreads();
    for (int off = 1; off < 1024; off <<= 1){
        int t = (threadIdx.x >= off) ? sb[threadIdx.x - off] : 0;
        __syncthreads();
        sb[threadIdx.x] += t;
        __syncthreads();
    }
    if (i < n){
        int ex = boff[blockIdx.x] + sb[threadIdx.x] - v;
        offsets[i] = ex; cursor[i] = ex;
    }
}

__global__ void k_fill(const int* __restrict__ ei, int E,
                       int* __restrict__ cursor, int* __restrict__ srclist){
    int e = blockIdx.x * 256 + threadIdx.x;
    if (e < E){
        int s = ei[e], d = ei[E + e];
        int pos = atomicAdd(&cursor[d], 1);
        srclist[pos] = s;
    }
}

// ------------- weight split: W[K][Nn] fp32 -> hi/lo bf16, [Nn][K] layout -------------
__global__ void k_split_w(const float* __restrict__ W, unsigned short* __restrict__ hi,
                          unsigned short* __restrict__ lo, int K, int Nn){
    int id = blockIdx.x * 256 + threadIdx.x;
    if (id >= K * Nn) return;
    int n = id / K, k = id - n * K;
    float v = W[(size_t)k * Nn + n];
    unsigned short h = f2bf(v);
    hi[id] = h;
    lo[id] = f2bf(v - bf2f(h));
}

// ------------- weight split, fragment-major pack -------------
// out idx -> frag = idx>>9 (=cg*(K/32)+kg), lane = (idx>>3)&63, j = idx&7
// element = W[k = kg*32 + (lane>>4)*8 + j][c = cg*16 + (lane&15)]
// => per-wave B-fragment load = one coalesced 1KB read.
__global__ void k_split_pack(const float* __restrict__ W, unsigned short* __restrict__ hi,
                             unsigned short* __restrict__ lo, int K, int Nn){
    int idx = blockIdx.x * 256 + threadIdx.x;
    if (idx >= K * Nn) return;
    int j = idx & 7;
    int lane = (idx >> 3) & 63;
    int frag = idx >> 9;
    int kgroups = K >> 5;
    int kg = frag % kgroups;
    int cg = frag / kgroups;
    int c = cg * 16 + (lane & 15);
    int k = kg * 32 + (lane >> 4) * 8 + j;
    float v = W[(size_t)k * Nn + c];
    unsigned short h = f2bf(v);
    hi[idx] = h;
    lo[idx] = f2bf(v - bf2f(h));
}

// ---------------- xs = x * dinv[row], width 128 ----------------
__global__ void k_scalerows(const float* __restrict__ x, const float* __restrict__ dinv,
                            float* __restrict__ xs, int total4){
    int id = blockIdx.x * 256 + threadIdx.x;
    if (id >= total4) return;
    int node = id >> 5;
    float d = dinv[node];
    float4 v = ld4(&x[(size_t)id * 4]);
    st4(&xs[(size_t)id * 4], make_float4(v.x*d, v.y*d, v.z*d, v.w*d));
}

// ---------------- CSR aggregate, width 128 ----------------
__global__ __launch_bounds__(256) void k_agg2(const float* __restrict__ in,
        const int* __restrict__ offsets, const int* __restrict__ srclist,
        const float* __restrict__ dinv, float* __restrict__ out, int n){
    int wid = (blockIdx.x * 256 + threadIdx.x) >> 6;
    int lane = threadIdx.x & 63;
    if (wid >= n) return;
    int f = lane * 2;
    float2 acc = *reinterpret_cast<const float2*>(&in[(size_t)wid * 128 + f]);
    int o0 = offsets[wid], o1 = offsets[wid + 1];
    int e = o0;
    for (; e + 3 < o1; e += 4){
        int s0 = srclist[e], s1 = srclist[e+1], s2 = srclist[e+2], s3 = srclist[e+3];
        float2 v0 = *reinterpret_cast<const float2*>(&in[(size_t)s0 * 128 + f]);
        float2 v1 = *reinterpret_cast<const float2*>(&in[(size_t)s1 * 128 + f]);
        float2 v2 = *reinterpret_cast<const float2*>(&in[(size_t)s2 * 128 + f]);
        float2 v3 = *reinterpret_cast<const float2*>(&in[(size_t)s3 * 128 + f]);
        acc.x += (v0.x + v1.x) + (v2.x + v3.x);
        acc.y += (v0.y + v1.y) + (v2.y + v3.y);
    }
    for (; e < o1; ++e){
        int s0 = srclist[e];
        float2 v0 = *reinterpret_cast<const float2*>(&in[(size_t)s0 * 128 + f]);
        acc.x += v0.x; acc.y += v0.y;
    }
    float d = dinv[wid];
    *reinterpret_cast<float2*>(&out[(size_t)wid * 128 + f]) = make_float2(acc.x * d, acc.y * d);
}

// ---------------- CSR aggregate, width 256 ----------------
__global__ __launch_bounds__(256) void k_agg4(const float* __restrict__ in,
        const int* __restrict__ offsets, const int* __restrict__ srclist,
        const float* __restrict__ dinv, float* __restrict__ out, int n){
    int wid = (blockIdx.x * 256 + threadIdx.x) >> 6;
    int lane = threadIdx.x & 63;
    if (wid >= n) return;
    int f = lane * 4;
    float4 acc = ld4(&in[(size_t)wid * 256 + f]);
    int o0 = offsets[wid], o1 = offsets[wid + 1];
    int e = o0;
    for (; e + 3 < o1; e += 4){
        int s0 = srclist[e], s1 = srclist[e+1], s2 = srclist[e+2], s3 = srclist[e+3];
        float4 v0 = ld4(&in[(size_t)s0 * 256 + f]);
        float4 v1 = ld4(&in[(size_t)s1 * 256 + f]);
        float4 v2 = ld4(&in[(size_t)s2 * 256 + f]);
        float4 v3 = ld4(&in[(size_t)s3 * 256 + f]);
        acc.x += (v0.x + v1.x) + (v2.x + v3.x);
        acc.y += (v0.y + v1.y) + (v2.y + v3.y);
        acc.z += (v0.z + v1.z) + (v2.z + v3.z);
        acc.w += (v0.w + v1.w) + (v2.w + v3.w);
    }
    for (; e < o1; ++e){
        int s0 = srclist[e];
        float4 v0 = ld4(&in[(size_t)s0 * 256 + f]);
        acc.x += v0.x; acc.y += v0.y; acc.z += v0.z; acc.w += v0.w;
    }
    float d = dinv[wid];
    st4(&out[(size_t)wid * 256 + f],
        make_float4(acc.x * d, acc.y * d, acc.z * d, acc.w * d));
}

// ---------------- MFMA bf16x3 GEMM (node-side) ----------------
template<bool RELU, bool POSTSCALE>
__global__ __launch_bounds__(256) void k_mgemm(
        const float* __restrict__ A, const unsigned short* __restrict__ Bh,
        const unsigned short* __restrict__ Bl, const float* __restrict__ bias,
        const float* __restrict__ pscale, float* __restrict__ C,
        int M, int K, int Nn){
    __shared__ unsigned short As_h[128][40], As_l[128][40];
    __shared__ unsigned short Bs_h[128][40], Bs_l[128][40];
    int tid = threadIdx.x;
    int l = tid & 63, w = tid >> 6;
    int wr = w >> 1, wc = w & 1;
    int row0 = blockIdx.x * 128, col0 = blockIdx.y * 128;
    int lr = l & 15, lg = l >> 4, lk = lg * 8;

    f32x4 acc[4][4] = {};

    for (int kt = 0; kt < K; kt += 32){
#pragma unroll
        for (int lp = 0; lp < 4; ++lp){
            int idx = tid + lp * 256;
            int r = idx >> 3, c4 = idx & 7;
            float4 v = make_float4(0.f, 0.f, 0.f, 0.f);
            if (row0 + r < M) v = ld4(&A[(size_t)(row0 + r) * K + kt + c4 * 4]);
            unsigned short h0 = f2bf(v.x), h1 = f2bf(v.y), h2 = f2bf(v.z), h3 = f2bf(v.w);
            unsigned short e0 = f2bf(v.x - bf2f(h0)), e1 = f2bf(v.y - bf2f(h1));
            unsigned short e2 = f2bf(v.z - bf2f(h2)), e3 = f2bf(v.w - bf2f(h3));
            *reinterpret_cast<uint2*>(&As_h[r][c4 * 4]) =
                make_uint2((unsigned)h0 | ((unsigned)h1 << 16), (unsigned)h2 | ((unsigned)h3 << 16));
            *reinterpret_cast<uint2*>(&As_l[r][c4 * 4]) =
                make_uint2((unsigned)e0 | ((unsigned)e1 << 16), (unsigned)e2 | ((unsigned)e3 << 16));
        }
#pragma unroll
        for (int lp = 0; lp < 2; ++lp){
            int idx = tid + lp * 256;
            int r = idx >> 2, c8 = idx & 3;
            size_t go = (size_t)(col0 + r) * K + kt + c8 * 8;
            *reinterpret_cast<uint4*>(&Bs_h[r][c8 * 8]) = *reinterpret_cast<const uint4*>(&Bh[go]);
            *reinterpret_cast<uint4*>(&Bs_l[r][c8 * 8]) = *reinterpret_cast<const uint4*>(&Bl[go]);
        }
        __syncthreads();

        short8 ah[4], al[4], bh[4], bl[4];
#pragma unroll
        for (int mi = 0; mi < 4; ++mi){
            ah[mi] = *reinterpret_cast<const short8*>(&As_h[wr * 64 + mi * 16 + lr][lk]);
            al[mi] = *reinterpret_cast<const short8*>(&As_l[wr * 64 + mi * 16 + lr][lk]);
        }
#pragma unroll
        for (int ni = 0; ni < 4; ++ni){
            bh[ni] = *reinterpret_cast<const short8*>(&Bs_h[wc * 64 + ni * 16 + lr][lk]);
            bl[ni] = *reinterpret_cast<const short8*>(&Bs_l[wc * 64 + ni * 16 + lr][lk]);
        }
#pragma unroll
        for (int mi = 0; mi < 4; ++mi)
#pragma unroll
            for (int ni = 0; ni < 4; ++ni)
                acc[mi][ni] = __builtin_amdgcn_mfma_f32_16x16x32_bf16(ah[mi], bh[ni], acc[mi][ni], 0, 0, 0);
#pragma unroll
        for (int mi = 0; mi < 4; ++mi)
#pragma unroll
            for (int ni = 0; ni < 4; ++ni)
                acc[mi][ni] = __builtin_amdgcn_mfma_f32_16x16x32_bf16(ah[mi], bl[ni], acc[mi][ni], 0, 0, 0);
#pragma unroll
        for (int mi = 0; mi < 4; ++mi)
#pragma unroll
            for (int ni = 0; ni < 4; ++ni)
                acc[mi][ni] = __builtin_amdgcn_mfma_f32_16x16x32_bf16(al[mi], bh[ni], acc[mi][ni], 0, 0, 0);
        __syncthreads();
    }

#pragma unroll
    for (int ni = 0; ni < 4; ++ni){
        int col = col0 + wc * 64 + ni * 16 + lr;
        float bv = bias[col];
#pragma unroll
        for (int mi = 0; mi < 4; ++mi){
#pragma unroll
            for (int rr = 0; rr < 4; ++rr){
                int grow = row0 + wr * 64 + mi * 16 + lg * 4 + rr;
                if (grow < M){
                    float v = acc[mi][ni][rr] + bv;
                    if (RELU) v = fmaxf(v, 0.f);
                    if (POSTSCALE) v *= pscale[grow];
                    C[(size_t)grow * Nn + col] = v;
                }
            }
        }
    }
}

// ---------------- fused decoder, round-4 structure ----------------
// 64 queries/block, 512 threads = 8 waves (2 row-groups x 4 col-groups).
// Phase 1: gather zc panel (64 x 256 fp32) -> split bf16 hi/lo -> LDS (one barrier)
// Phase 2: stage-1 GEMM, 8 barrier-free K-steps; weights = packed frags from L2
// Phase 3: u1 epilogue (exact fp32 rank-1 terms), relu, split -> SAME LDS
// Phase 4: stage-2 GEMM, 8 barrier-free K-steps
// Phase 5: relu+bd2, dot Wd3, LDS reduce, sigmoid
__global__ __launch_bounds__(512, 4) void k_dec(
        const float* __restrict__ z, const int* __restrict__ qe,
        const int* __restrict__ iv, const int* __restrict__ pid,
        const unsigned short* __restrict__ W1h, const unsigned short* __restrict__ W1l,
        const float* __restrict__ Wd1, const float* __restrict__ bd1,
        const unsigned short* __restrict__ W2h, const unsigned short* __restrict__ W2l,
        const float* __restrict__ bd2, const float* __restrict__ Wd3,
        const float* __restrict__ bd3, float* __restrict__ out, int Q){
    __shared__ unsigned short As_h[64][264];
    __shared__ unsigned short As_l[64][264];
    __shared__ int   sQs[64], sQd[64];
    __shared__ float sIdf[64], sSp[64];

    int tid = threadIdx.x;
    int q0 = blockIdx.x * 64;
    if (tid < 64){
        int q = q0 + tid;
        int qs = 0, qd = 0; float idf = 0.f, sp = 0.f;
        if (q < Q){
            qs = qe[q]; qd = qe[Q + q];
            idf = (float)(iv[qd] - iv[qs]);
            sp = (pid[qs] == pid[qd]) ? 1.f : 0.f;
        }
        sQs[tid] = qs; sQd[tid] = qd; sIdf[tid] = idf; sSp[tid] = sp;
    }
    __syncthreads();

    // ---- phase 1: gather + split full A panel (64 rows x 256 cols) ----
#pragma unroll
    for (int lp = 0; lp < 4; ++lp){
        int ch = tid + lp * 512;          // 2048 chunks of 8 floats
        int r = ch >> 5, c8 = ch & 31;
        int srow = (c8 < 16) ? sQs[r] : sQd[r];
        int colb = (c8 & 15) * 8;
        float4 v0 = ld4(&z[(size_t)srow * 128 + colb]);
        float4 v1 = ld4(&z[(size_t)srow * 128 + colb + 4]);
        float vv[8] = {v0.x, v0.y, v0.z, v0.w, v1.x, v1.y, v1.z, v1.w};
        unsigned short hh[8], ll[8];
#pragma unroll
        for (int j = 0; j < 8; ++j){
            hh[j] = f2bf(vv[j]);
            ll[j] = f2bf(vv[j] - bf2f(hh[j]));
        }
        *reinterpret_cast<uint4*>(&As_h[r][c8 * 8]) = *reinterpret_cast<uint4*>(hh);
        *reinterpret_cast<uint4*>(&As_l[r][c8 * 8]) = *reinterpret_cast<uint4*>(ll);
    }
    __syncthreads();

    int l = tid & 63, w = tid >> 6;
    int wr = w >> 2, wc = w & 3;
    int lr = l & 15, lg = l >> 4, lk = lg * 8;

    // ---- phase 2: stage-1 GEMM (rows wr*32.., cols wc*64..), no barriers ----
    f32x4 acc1[2][4] = {};
#pragma unroll
    for (int ks = 0; ks < 8; ++ks){
        int kt = ks * 32;
        short8 ah[2], al[2], bh[4], bl[4];
#pragma unroll
        for (int mi = 0; mi < 2; ++mi){
            int row = wr * 32 + mi * 16 + lr;
            ah[mi] = *reinterpret_cast<const short8*>(&As_h[row][kt + lk]);
            al[mi] = *reinterpret_cast<const short8*>(&As_l[row][kt + lk]);
        }
#pragma unroll
        for (int ni = 0; ni < 4; ++ni){
            size_t off = ((size_t)((wc * 4 + ni) * 8 + ks) << 9) + l * 8;
            bh[ni] = *reinterpret_cast<const short8*>(&W1h[off]);
            bl[ni] = *reinterpret_cast<const short8*>(&W1l[off]);
        }
#pragma unroll
        for (int mi = 0; mi < 2; ++mi)
#pragma unroll
            for (int ni = 0; ni < 4; ++ni)
                acc1[mi][ni] = __builtin_amdgcn_mfma_f32_16x16x32_bf16(ah[mi], bh[ni], acc1[mi][ni], 0, 0, 0);
#pragma unroll
        for (int mi = 0; mi < 2; ++mi)
#pragma unroll
            for (int ni = 0; ni < 4; ++ni)
                acc1[mi][ni] = __builtin_amdgcn_mfma_f32_16x16x32_bf16(ah[mi], bl[ni], acc1[mi][ni], 0, 0, 0);
#pragma unroll
        for (int mi = 0; mi < 2; ++mi)
#pragma unroll
            for (int ni = 0; ni < 4; ++ni)
                acc1[mi][ni] = __builtin_amdgcn_mfma_f32_16x16x32_bf16(al[mi], bh[ni], acc1[mi][ni], 0, 0, 0);
    }
    __syncthreads();   // everyone done READING A panel

    // ---- phase 3: u1 epilogue -> overwrite LDS panel with U (hi/lo) ----
#pragma unroll
    for (int ni = 0; ni < 4; ++ni){
        int c = wc * 64 + ni * 16 + lr;
        float bv  = bd1[c];
        float wiv = Wd1[256 * 256 + c];
        float wsv = Wd1[257 * 256 + c];
#pragma unroll
        for (int mi = 0; mi < 2; ++mi){
#pragma unroll
            for (int rr = 0; rr < 4; ++rr){
                int r = wr * 32 + mi * 16 + lg * 4 + rr;
                float u = acc1[mi][ni][rr] + bv + sIdf[r] * wiv + sSp[r] * wsv;
                u = fmaxf(u, 0.f);
                unsigned short h = f2bf(u);
                As_h[r][c] = h;
                As_l[r][c] = f2bf(u - bf2f(h));
            }
        }
    }
    __syncthreads();

    // ---- phase 4: stage-2 GEMM (cols wc*32..), no barriers ----
    f32x4 acc2[2][2] = {};
#pragma unroll
    for (int ks = 0; ks < 8; ++ks){
        int kt = ks * 32;
        short8 ah[2], al[2], bh[2], bl[2];
#pragma unroll
        for (int mi = 0; mi < 2; ++mi){
            int row = wr * 32 + mi * 16 + lr;
            ah[mi] = *reinterpret_cast<const short8*>(&As_h[row][kt + lk]);
            al[mi] = *reinterpret_cast<const short8*>(&As_l[row][kt + lk]);
        }
#pragma unroll
        for (int ni = 0; ni < 2; ++ni){
            size_t off = ((size_t)((wc * 2 + ni) * 8 + ks) << 9) + l * 8;
            bh[ni] = *reinterpret_cast<const short8*>(&W2h[off]);
            bl[ni] = *reinterpret_cast<const short8*>(&W2l[off]);
        }
#pragma unroll
        for (int mi = 0; mi < 2; ++mi)
#pragma unroll
            for (int ni = 0; ni < 2; ++ni)
                acc2[mi][ni] = __builtin_amdgcn_mfma_f32_16x16x32_bf16(ah[mi], bh[ni], acc2[mi][ni], 0, 0, 0);
#pragma unroll
        for (int mi = 0; mi < 2; ++mi)
#pragma unroll
            for (int ni = 0; ni < 2; ++ni)
                acc2[mi][ni] = __builtin_amdgcn_mfma_f32_16x16x32_bf16(ah[mi], bl[ni], acc2[mi][ni], 0, 0, 0);
#pragma unroll
        for (int mi = 0; mi < 2; ++mi)
#pragma unroll
            for (int ni = 0; ni < 2; ++ni)
                acc2[mi][ni] = __builtin_amdgcn_mfma_f32_16x16x32_bf16(al[mi], bh[ni], acc2[mi][ni], 0, 0, 0);
    }
    __syncthreads();   // done reading U; LDS free for reduction

    // ---- phase 5: relu(+bd2), dot Wd3, reduce, sigmoid ----
    float* red = (float*)&As_h[0][0];   // [64][65] floats = 16.6 KB < As_h
    float psum[2][4] = {};
#pragma unroll
    for (int ni = 0; ni < 2; ++ni){
        int c = wc * 32 + ni * 16 + lr;
        float b2v = bd2[c];
        float w3v = Wd3[c];
#pragma unroll
        for (int mi = 0; mi < 2; ++mi)
#pragma unroll
            for (int rr = 0; rr < 4; ++rr)
                psum[mi][rr] += fmaxf(acc2[mi][ni][rr] + b2v, 0.f) * w3v;
    }
#pragma unroll
    for (int mi = 0; mi < 2; ++mi)
#pragma unroll
        for (int rr = 0; rr < 4; ++rr){
            int r = wr * 32 + mi * 16 + lg * 4 + rr;
            red[r * 65 + wc * 16 + lr] = psum[mi][rr];
        }
    __syncthreads();

    {
        int qr = tid >> 3, part = tid & 7;
        float s = 0.f;
#pragma unroll
        for (int j = 0; j < 8; ++j) s += red[qr * 65 + part * 8 + j];
        s += __shfl_xor(s, 1, 8);
        s += __shfl_xor(s, 2, 8);
        s += __shfl_xor(s, 4, 8);
        int q = q0 + qr;
        if (part == 0 && q < Q) out[q] = 1.f / (1.f + expf(-(s + bd3[0])));
    }
}

// ---------------- launch ----------------
extern "C" void kernel_launch(void* const* d_in, const int* in_sizes, int n_in,
                              void* d_out, int out_size, void* d_ws, size_t ws_size,
                              hipStream_t stream){
    const float* x   = (const float*)d_in[0];
    const int*   ei  = (const int*)  d_in[1];
    const int*   qe  = (const int*)  d_in[2];
    const int*   iv  = (const int*)  d_in[3];
    const int*   pid = (const int*)  d_in[4];
    const float* W1  = (const float*)d_in[5];
    const float* b1  = (const float*)d_in[6];
    const float* W2  = (const float*)d_in[7];
    const float* b2  = (const float*)d_in[8];
    const float* Wfc = (const float*)d_in[9];
    const float* bfc = (const float*)d_in[10];
    const float* Wd1 = (const float*)d_in[11];
    const float* bd1 = (const float*)d_in[12];
    const float* Wd2 = (const float*)d_in[13];
    const float* bd2 = (const float*)d_in[14];
    const float* Wd3 = (const float*)d_in[15];
    const float* bd3 = (const float*)d_in[16];
    float* out = (float*)d_out;

    const int N = in_sizes[3];
    const int E = in_sizes[1] / 2;
    const int Q = in_sizes[2] / 2;

    char* p = (char*)d_ws;
    auto alloc = [&](size_t bytes) -> char* {
        char* r = p; p += (bytes + 255) & ~(size_t)255; return r;
    };
    int*   counts  = (int*)  alloc((size_t)N * 4);
    int*   offsets = (int*)  alloc((size_t)(N + 1) * 4);
    int*   cursor  = (int*)  alloc((size_t)(N + 1) * 4);
    int*   srclist = (int*)  alloc((size_t)E * 4);
    float* dinv    = (float*)alloc((size_t)N * 4);
    int*   bsum    = (int*)  alloc(1024 * 4);
    int*   boff    = (int*)  alloc(1024 * 4);
    unsigned short* w1h  = (unsigned short*)alloc(256 * 128 * 2);
    unsigned short* w1l  = (unsigned short*)alloc(256 * 128 * 2);
    unsigned short* w2h  = (unsigned short*)alloc(256 * 256 * 2);
    unsigned short* w2l  = (unsigned short*)alloc(256 * 256 * 2);
    unsigned short* wfh  = (unsigned short*)alloc(128 * 256 * 2);
    unsigned short* wfl  = (unsigned short*)alloc(128 * 256 * 2);
    unsigned short* wd1h = (unsigned short*)alloc(256 * 256 * 2);  // packed frags
    unsigned short* wd1l = (unsigned short*)alloc(256 * 256 * 2);
    unsigned short* wd2h = (unsigned short*)alloc(128 * 256 * 2);  // packed frags
    unsigned short* wd2l = (unsigned short*)alloc(128 * 256 * 2);
    float* P1 = (float*)alloc((size_t)N * 256 * 4);
    float* P2 = (float*)alloc((size_t)N * 256 * 4);

    float* xs  = P2;                       // [N,128]
    float* ag1 = P2 + (size_t)N * 128;     // [N,128]
    float* h1s = P1;                       // [N,256]
    float* ag2 = P2;                       // [N,256]
    float* h2  = P1;                       // [N,256]
    float* z   = P2;                       // [N,128]

    const int nb = (N + 1023) / 1024;
    dim3 blk(256);

    hipMemsetAsync(counts, 0, (size_t)N * 4, stream);
    k_count   <<<dim3((E + 255) / 256), blk,        0, stream>>>(ei, E, counts);
    k_blocksum<<<dim3(nb),              dim3(1024), 0, stream>>>(counts, N, bsum);
    k_bscan   <<<dim3(1),               dim3(64),   0, stream>>>(bsum, nb, boff, offsets, N);
    k_offsets <<<dim3(nb),              dim3(1024), 0, stream>>>(counts, N, boff, offsets, cursor, dinv);
    k_fill    <<<dim3((E + 255) / 256), blk,        0, stream>>>(ei, E, cursor, srclist);

    // weight preprocessing
    k_split_w   <<<dim3(128), blk, 0, stream>>>(W1,  w1h,  w1l,  128, 256);
    k_split_w   <<<dim3(256), blk, 0, stream>>>(W2,  w2h,  w2l,  256, 256);
    k_split_w   <<<dim3(128), blk, 0, stream>>>(Wfc, wfh,  wfl,  256, 128);
    k_split_pack<<<dim3(256), blk, 0, stream>>>(Wd1, wd1h, wd1l, 256, 256);
    k_split_pack<<<dim3(128), blk, 0, stream>>>(Wd2, wd2h, wd2l, 256, 128);

    // encoder
    k_scalerows<<<dim3((N * 32 + 255) / 256), blk, 0, stream>>>(x, dinv, xs, N * 32);
    k_agg2<<<dim3(N / 4), blk, 0, stream>>>(xs, offsets, srclist, dinv, ag1, N);
    k_mgemm<true,  true ><<<dim3((N + 127) / 128, 2), blk, 0, stream>>>(ag1, w1h, w1l, b1, dinv, h1s, N, 128, 256);
    k_agg4<<<dim3(N / 4), blk, 0, stream>>>(h1s, offsets, srclist, dinv, ag2, N);
    k_mgemm<true,  false><<<dim3((N + 127) / 128, 2), blk, 0, stream>>>(ag2, w2h, w2l, b2, nullptr, h2, N, 256, 256);
    k_mgemm<false, false><<<dim3((N + 127) / 128, 1), blk, 0, stream>>>(h2, wfh, wfl, bfc, nullptr, z, N, 256, 128);

    // fused decoder
    k_dec<<<dim3((Q + 63) / 64), dim3(512), 0, stream>>>(z, qe, iv, pid,
                                                         wd1h, wd1l, Wd1, bd1,
                                                         wd2h, wd2l, bd2, Wd3, bd3, out, Q);
}

// Round 9
// 1216.337 us; speedup vs baseline: 1.4581x; 1.0028x over previous
//
#include <hip/hip_runtime.h>
#include <math.h>

// NextIntegerLinkPredictor, round 9 (= round-6 kernel, third resubmission after
// GPUAcquisitionTimeouts; never executed, no counter evidence against it).
// vs round 5: all fp32->split-bf16 conversions fused into producer epilogues.
//  - GEMM A-inputs (ag1, ag2, h2) and z stored as pre-split hi/lo bf16 pairs
//    (same bytes as fp32; staging becomes pure uint4 copies, no f2bf VALU).
//  - k_dec phase-1 gathers pre-split zh/zl (no converts).
//  - k_scalerows deleted: k_agg2 reads x with inline dinv[s] scaling.

typedef __attribute__((ext_vector_type(8))) short short8;
typedef __attribute__((ext_vector_type(4))) float f32x4;

__device__ __forceinline__ float4 ld4(const float* p){ return *reinterpret_cast<const float4*>(p); }
__device__ __forceinline__ void st4(float* p, float4 v){ *reinterpret_cast<float4*>(p) = v; }
__device__ __forceinline__ unsigned short f2bf(float f){
    union{float f; unsigned u;} v; v.f = f;
    unsigned r = (v.u + 0x7FFFu + ((v.u >> 16) & 1u)) >> 16;
    return (unsigned short)r;
}
__device__ __forceinline__ float bf2f(unsigned short b){
    union{unsigned u; float f;} v; v.u = ((unsigned)b) << 16; return v.f;
}

// ---------------- CSR build ----------------
__global__ void k_count(const int* __restrict__ ei, int E, int* __restrict__ counts){
    int e = blockIdx.x * 256 + threadIdx.x;
    if (e < E) atomicAdd(&counts[ei[E + e]], 1);
}

__global__ __launch_bounds__(1024) void k_blocksum(const int* __restrict__ counts, int n,
                                                   int* __restrict__ bsum){
    __shared__ int sb[1024];
    int i = blockIdx.x * 1024 + threadIdx.x;
    sb[threadIdx.x] = (i < n) ? counts[i] : 0;
    __syncthreads();
    for (int off = 512; off > 0; off >>= 1){
        if (threadIdx.x < off) sb[threadIdx.x] += sb[threadIdx.x + off];
        __syncthreads();
    }
    if (threadIdx.x == 0) bsum[blockIdx.x] = sb[0];
}

__global__ void k_bscan(const int* __restrict__ bsum, int nb,
                        int* __restrict__ boff, int* __restrict__ offsets, int n){
    if (threadIdx.x == 0){
        int run = 0;
        for (int b = 0; b < nb; ++b){ boff[b] = run; run += bsum[b]; }
        offsets[n] = run;
    }
}

__global__ __launch_bounds__(1024) void k_offsets(const int* __restrict__ counts, int n,
                                                  const int* __restrict__ boff,
                                                  int* __restrict__ offsets,
                                                  int* __restrict__ cursor,
                                                  float* __restrict__ dinv){
    __shared__ int sb[1024];
    int i = blockIdx.x * 1024 + threadIdx.x;
    int v = (i < n) ? counts[i] : 0;
    if (i < n) dinv[i] = rsqrtf((float)(v + 1));   // +1 self-loop
    sb[threadIdx.x] = v;
    __syncthreads();
    for (int off = 1; off < 1024; off <<= 1){
        int t = (threadIdx.x >= off) ? sb[threadIdx.x - off] : 0;
        __syncthreads();
        sb[threadIdx.x] += t;
        __syncthreads();
    }
    if (i < n){
        int ex = boff[blockIdx.x] + sb[threadIdx.x] - v;
        offsets[i] = ex; cursor[i] = ex;
    }
}

__global__ void k_fill(const int* __restrict__ ei, int E,
                       int* __restrict__ cursor, int* __restrict__ srclist){
    int e = blockIdx.x * 256 + threadIdx.x;
    if (e < E){
        int s = ei[e], d = ei[E + e];
        int pos = atomicAdd(&cursor[d], 1);
        srclist[pos] = s;
    }
}

// ------------- weight split: W[K][Nn] fp32 -> hi/lo bf16, [Nn][K] layout -------------
__global__ void k_split_w(const float* __restrict__ W, unsigned short* __restrict__ hi,
                          unsigned short* __restrict__ lo, int K, int Nn){
    int id = blockIdx.x * 256 + threadIdx.x;
    if (id >= K * Nn) return;
    int n = id / K, k = id - n * K;
    float v = W[(size_t)k * Nn + n];
    unsigned short h = f2bf(v);
    hi[id] = h;
    lo[id] = f2bf(v - bf2f(h));
}

// ------------- weight split, fragment-major pack (k_dec weights) -------------
// out idx -> frag = idx>>9 (=cg*(K/32)+kg), lane = (idx>>3)&63, j = idx&7
// element = W[k = kg*32 + (lane>>4)*8 + j][c = cg*16 + (lane&15)]
__global__ void k_split_pack(const float* __restrict__ W, unsigned short* __restrict__ hi,
                             unsigned short* __restrict__ lo, int K, int Nn){
    int idx = blockIdx.x * 256 + threadIdx.x;
    if (idx >= K * Nn) return;
    int j = idx & 7;
    int lane = (idx >> 3) & 63;
    int frag = idx >> 9;
    int kgroups = K >> 5;
    int kg = frag % kgroups;
    int cg = frag / kgroups;
    int c = cg * 16 + (lane & 15);
    int k = kg * 32 + (lane >> 4) * 8 + j;
    float v = W[(size_t)k * Nn + c];
    unsigned short h = f2bf(v);
    hi[idx] = h;
    lo[idx] = f2bf(v - bf2f(h));
}

// ---------------- CSR aggregate, width 128: reads x fp32, inline dinv[s], split out ----
__global__ __launch_bounds__(256) void k_agg2(const float* __restrict__ x,
        const int* __restrict__ offsets, const int* __restrict__ srclist,
        const float* __restrict__ dinv,
        unsigned short* __restrict__ outh, unsigned short* __restrict__ outl, int n){
    int wid = (blockIdx.x * 256 + threadIdx.x) >> 6;
    int lane = threadIdx.x & 63;
    if (wid >= n) return;
    int f = lane * 2;
    float dself = dinv[wid];
    float2 xv = *reinterpret_cast<const float2*>(&x[(size_t)wid * 128 + f]);
    float2 acc = make_float2(xv.x * dself, xv.y * dself);
    int o0 = offsets[wid], o1 = offsets[wid + 1];
    int e = o0;
    for (; e + 3 < o1; e += 4){
        int s0 = srclist[e], s1 = srclist[e+1], s2 = srclist[e+2], s3 = srclist[e+3];
        float d0 = dinv[s0], d1 = dinv[s1], d2 = dinv[s2], d3 = dinv[s3];
        float2 v0 = *reinterpret_cast<const float2*>(&x[(size_t)s0 * 128 + f]);
        float2 v1 = *reinterpret_cast<const float2*>(&x[(size_t)s1 * 128 + f]);
        float2 v2 = *reinterpret_cast<const float2*>(&x[(size_t)s2 * 128 + f]);
        float2 v3 = *reinterpret_cast<const float2*>(&x[(size_t)s3 * 128 + f]);
        acc.x += v0.x * d0 + v1.x * d1 + v2.x * d2 + v3.x * d3;
        acc.y += v0.y * d0 + v1.y * d1 + v2.y * d2 + v3.y * d3;
    }
    for (; e < o1; ++e){
        int s0 = srclist[e];
        float d0 = dinv[s0];
        float2 v0 = *reinterpret_cast<const float2*>(&x[(size_t)s0 * 128 + f]);
        acc.x += v0.x * d0; acc.y += v0.y * d0;
    }
    float vx = acc.x * dself, vy = acc.y * dself;
    unsigned short hx = f2bf(vx), hy = f2bf(vy);
    size_t o = (size_t)wid * 128 + f;
    *reinterpret_cast<unsigned*>(&outh[o]) = (unsigned)hx | ((unsigned)hy << 16);
    *reinterpret_cast<unsigned*>(&outl[o]) =
        (unsigned)f2bf(vx - bf2f(hx)) | ((unsigned)f2bf(vy - bf2f(hy)) << 16);
}

// ---------------- CSR aggregate, width 256: fp32 in, split out ----------------
__global__ __launch_bounds__(256) void k_agg4(const float* __restrict__ in,
        const int* __restrict__ offsets, const int* __restrict__ srclist,
        const float* __restrict__ dinv,
        unsigned short* __restrict__ outh, unsigned short* __restrict__ outl, int n){
    int wid = (blockIdx.x * 256 + threadIdx.x) >> 6;
    int lane = threadIdx.x & 63;
    if (wid >= n) return;
    int f = lane * 4;
    float4 acc = ld4(&in[(size_t)wid * 256 + f]);   // self (input pre-scaled by dinv[row])
    int o0 = offsets[wid], o1 = offsets[wid + 1];
    int e = o0;
    for (; e + 3 < o1; e += 4){
        int s0 = srclist[e], s1 = srclist[e+1], s2 = srclist[e+2], s3 = srclist[e+3];
        float4 v0 = ld4(&in[(size_t)s0 * 256 + f]);
        float4 v1 = ld4(&in[(size_t)s1 * 256 + f]);
        float4 v2 = ld4(&in[(size_t)s2 * 256 + f]);
        float4 v3 = ld4(&in[(size_t)s3 * 256 + f]);
        acc.x += (v0.x + v1.x) + (v2.x + v3.x);
        acc.y += (v0.y + v1.y) + (v2.y + v3.y);
        acc.z += (v0.z + v1.z) + (v2.z + v3.z);
        acc.w += (v0.w + v1.w) + (v2.w + v3.w);
    }
    for (; e < o1; ++e){
        int s0 = srclist[e];
        float4 v0 = ld4(&in[(size_t)s0 * 256 + f]);
        acc.x += v0.x; acc.y += v0.y; acc.z += v0.z; acc.w += v0.w;
    }
    float d = dinv[wid];
    float vv[4] = {acc.x * d, acc.y * d, acc.z * d, acc.w * d};
    unsigned short hh[4], ll[4];
#pragma unroll
    for (int j = 0; j < 4; ++j){
        hh[j] = f2bf(vv[j]);
        ll[j] = f2bf(vv[j] - bf2f(hh[j]));
    }
    size_t o = (size_t)wid * 256 + f;
    *reinterpret_cast<uint2*>(&outh[o]) =
        make_uint2((unsigned)hh[0] | ((unsigned)hh[1] << 16), (unsigned)hh[2] | ((unsigned)hh[3] << 16));
    *reinterpret_cast<uint2*>(&outl[o]) =
        make_uint2((unsigned)ll[0] | ((unsigned)ll[1] << 16), (unsigned)ll[2] | ((unsigned)ll[3] << 16));
}

// ---------------- MFMA bf16x3 GEMM, pre-split A ----------------
// A: hi/lo bf16 [M][K]. W: hi/lo bf16 [Nn][K]. BM=BN=128, BK=32, 4 waves 2x2.
// SPLITOUT: write C as hi/lo pair; else fp32.
template<bool RELU, bool POSTSCALE, bool SPLITOUT>
__global__ __launch_bounds__(256) void k_mgemm(
        const unsigned short* __restrict__ Ah, const unsigned short* __restrict__ Al,
        const unsigned short* __restrict__ Bh, const unsigned short* __restrict__ Bl,
        const float* __restrict__ bias, const float* __restrict__ pscale,
        float* __restrict__ C, unsigned short* __restrict__ Ch,
        unsigned short* __restrict__ Cl, int M, int K, int Nn){
    __shared__ unsigned short As_h[128][40], As_l[128][40];
    __shared__ unsigned short Bs_h[128][40], Bs_l[128][40];
    int tid = threadIdx.x;
    int l = tid & 63, w = tid >> 6;
    int wr = w >> 1, wc = w & 1;
    int row0 = blockIdx.x * 128, col0 = blockIdx.y * 128;
    int lr = l & 15, lg = l >> 4, lk = lg * 8;

    f32x4 acc[4][4] = {};

    for (int kt = 0; kt < K; kt += 32){
        // A tile: 128x32 hi+lo; pure byte copies (pre-split)
#pragma unroll
        for (int lp = 0; lp < 2; ++lp){
            int idx = tid + lp * 256;
            int r = idx >> 2, c8 = idx & 3;
            size_t go = (size_t)(row0 + r) * K + kt + c8 * 8;
            uint4 vh = make_uint4(0,0,0,0), vl = make_uint4(0,0,0,0);
            if (row0 + r < M){
                vh = *reinterpret_cast<const uint4*>(&Ah[go]);
                vl = *reinterpret_cast<const uint4*>(&Al[go]);
            }
            *reinterpret_cast<uint4*>(&As_h[r][c8 * 8]) = vh;
            *reinterpret_cast<uint4*>(&As_l[r][c8 * 8]) = vl;
        }
        // B tile: 128x32 from [Nn][K]
#pragma unroll
        for (int lp = 0; lp < 2; ++lp){
            int idx = tid + lp * 256;
            int r = idx >> 2, c8 = idx & 3;
            size_t go = (size_t)(col0 + r) * K + kt + c8 * 8;
            *reinterpret_cast<uint4*>(&Bs_h[r][c8 * 8]) = *reinterpret_cast<const uint4*>(&Bh[go]);
            *reinterpret_cast<uint4*>(&Bs_l[r][c8 * 8]) = *reinterpret_cast<const uint4*>(&Bl[go]);
        }
        __syncthreads();

        short8 ah[4], al[4], bh[4], bl[4];
#pragma unroll
        for (int mi = 0; mi < 4; ++mi){
            ah[mi] = *reinterpret_cast<const short8*>(&As_h[wr * 64 + mi * 16 + lr][lk]);
            al[mi] = *reinterpret_cast<const short8*>(&As_l[wr * 64 + mi * 16 + lr][lk]);
        }
#pragma unroll
        for (int ni = 0; ni < 4; ++ni){
            bh[ni] = *reinterpret_cast<const short8*>(&Bs_h[wc * 64 + ni * 16 + lr][lk]);
            bl[ni] = *reinterpret_cast<const short8*>(&Bs_l[wc * 64 + ni * 16 + lr][lk]);
        }
#pragma unroll
        for (int mi = 0; mi < 4; ++mi)
#pragma unroll
            for (int ni = 0; ni < 4; ++ni)
                acc[mi][ni] = __builtin_amdgcn_mfma_f32_16x16x32_bf16(ah[mi], bh[ni], acc[mi][ni], 0, 0, 0);
#pragma unroll
        for (int mi = 0; mi < 4; ++mi)
#pragma unroll
            for (int ni = 0; ni < 4; ++ni)
                acc[mi][ni] = __builtin_amdgcn_mfma_f32_16x16x32_bf16(ah[mi], bl[ni], acc[mi][ni], 0, 0, 0);
#pragma unroll
        for (int mi = 0; mi < 4; ++mi)
#pragma unroll
            for (int ni = 0; ni < 4; ++ni)
                acc[mi][ni] = __builtin_amdgcn_mfma_f32_16x16x32_bf16(al[mi], bh[ni], acc[mi][ni], 0, 0, 0);
        __syncthreads();
    }

#pragma unroll
    for (int ni = 0; ni < 4; ++ni){
        int col = col0 + wc * 64 + ni * 16 + lr;
        float bv = bias[col];
#pragma unroll
        for (int mi = 0; mi < 4; ++mi){
#pragma unroll
            for (int rr = 0; rr < 4; ++rr){
                int grow = row0 + wr * 64 + mi * 16 + lg * 4 + rr;
                if (grow < M){
                    float v = acc[mi][ni][rr] + bv;
                    if (RELU) v = fmaxf(v, 0.f);
                    if (POSTSCALE) v *= pscale[grow];
                    if (SPLITOUT){
                        unsigned short h = f2bf(v);
                        Ch[(size_t)grow * Nn + col] = h;
                        Cl[(size_t)grow * Nn + col] = f2bf(v - bf2f(h));
                    } else {
                        C[(size_t)grow * Nn + col] = v;
                    }
                }
            }
        }
    }
}

// ---------------- fused decoder ----------------
// 64 queries/block, 512 threads = 8 waves (2 row-groups x 4 col-groups).
// Phase 1: gather PRE-SPLIT zh/zl panel -> LDS (pure copy, no converts)
// Phase 2: stage-1 GEMM, 8 barrier-free K-steps, packed frag weights
// Phase 3: u1 epilogue (exact fp32 rank-1 terms) -> same LDS
// Phase 4: stage-2 GEMM  Phase 5: reduce + sigmoid
__global__ __launch_bounds__(512, 4) void k_dec(
        const unsigned short* __restrict__ zh, const unsigned short* __restrict__ zl,
        const int* __restrict__ qe,
        const int* __restrict__ iv, const int* __restrict__ pid,
        const unsigned short* __restrict__ W1h, const unsigned short* __restrict__ W1l,
        const float* __restrict__ Wd1, const float* __restrict__ bd1,
        const unsigned short* __restrict__ W2h, const unsigned short* __restrict__ W2l,
        const float* __restrict__ bd2, const float* __restrict__ Wd3,
        const float* __restrict__ bd3, float* __restrict__ out, int Q){
    __shared__ unsigned short As_h[64][264];
    __shared__ unsigned short As_l[64][264];
    __shared__ int   sQs[64], sQd[64];
    __shared__ float sIdf[64], sSp[64];

    int tid = threadIdx.x;
    int q0 = blockIdx.x * 64;
    if (tid < 64){
        int q = q0 + tid;
        int qs = 0, qd = 0; float idf = 0.f, sp = 0.f;
        if (q < Q){
            qs = qe[q]; qd = qe[Q + q];
            idf = (float)(iv[qd] - iv[qs]);
            sp = (pid[qs] == pid[qd]) ? 1.f : 0.f;
        }
        sQs[tid] = qs; sQd[tid] = qd; sIdf[tid] = idf; sSp[tid] = sp;
    }
    __syncthreads();

    // ---- phase 1: gather pre-split panel (64 rows x 256 cols) ----
#pragma unroll
    for (int lp = 0; lp < 4; ++lp){
        int ch = tid + lp * 512;          // 2048 chunks of 8 bf16
        int r = ch >> 5, c8 = ch & 31;
        int srow = (c8 < 16) ? sQs[r] : sQd[r];
        size_t go = (size_t)srow * 128 + (c8 & 15) * 8;
        *reinterpret_cast<uint4*>(&As_h[r][c8 * 8]) = *reinterpret_cast<const uint4*>(&zh[go]);
        *reinterpret_cast<uint4*>(&As_l[r][c8 * 8]) = *reinterpret_cast<const uint4*>(&zl[go]);
    }
    __syncthreads();

    int l = tid & 63, w = tid >> 6;
    int wr = w >> 2, wc = w & 3;
    int lr = l & 15, lg = l >> 4, lk = lg * 8;

    // ---- phase 2: stage-1 GEMM, no barriers ----
    f32x4 acc1[2][4] = {};
#pragma unroll
    for (int ks = 0; ks < 8; ++ks){
        int kt = ks * 32;
        short8 ah[2], al[2], bh[4], bl[4];
#pragma unroll
        for (int mi = 0; mi < 2; ++mi){
            int row = wr * 32 + mi * 16 + lr;
            ah[mi] = *reinterpret_cast<const short8*>(&As_h[row][kt + lk]);
            al[mi] = *reinterpret_cast<const short8*>(&As_l[row][kt + lk]);
        }
#pragma unroll
        for (int ni = 0; ni < 4; ++ni){
            size_t off = ((size_t)((wc * 4 + ni) * 8 + ks) << 9) + l * 8;
            bh[ni] = *reinterpret_cast<const short8*>(&W1h[off]);
            bl[ni] = *reinterpret_cast<const short8*>(&W1l[off]);
        }
#pragma unroll
        for (int mi = 0; mi < 2; ++mi)
#pragma unroll
            for (int ni = 0; ni < 4; ++ni)
                acc1[mi][ni] = __builtin_amdgcn_mfma_f32_16x16x32_bf16(ah[mi], bh[ni], acc1[mi][ni], 0, 0, 0);
#pragma unroll
        for (int mi = 0; mi < 2; ++mi)
#pragma unroll
            for (int ni = 0; ni < 4; ++ni)
                acc1[mi][ni] = __builtin_amdgcn_mfma_f32_16x16x32_bf16(ah[mi], bl[ni], acc1[mi][ni], 0, 0, 0);
#pragma unroll
        for (int mi = 0; mi < 2; ++mi)
#pragma unroll
            for (int ni = 0; ni < 4; ++ni)
                acc1[mi][ni] = __builtin_amdgcn_mfma_f32_16x16x32_bf16(al[mi], bh[ni], acc1[mi][ni], 0, 0, 0);
    }
    __syncthreads();   // all waves done reading A panel

    // ---- phase 3: u1 epilogue -> overwrite LDS panel ----
#pragma unroll
    for (int ni = 0; ni < 4; ++ni){
        int c = wc * 64 + ni * 16 + lr;
        float bv  = bd1[c];
        float wiv = Wd1[256 * 256 + c];
        float wsv = Wd1[257 * 256 + c];
#pragma unroll
        for (int mi = 0; mi < 2; ++mi){
#pragma unroll
            for (int rr = 0; rr < 4; ++rr){
                int r = wr * 32 + mi * 16 + lg * 4 + rr;
                float u = acc1[mi][ni][rr] + bv + sIdf[r] * wiv + sSp[r] * wsv;
                u = fmaxf(u, 0.f);
                unsigned short h = f2bf(u);
                As_h[r][c] = h;
                As_l[r][c] = f2bf(u - bf2f(h));
            }
        }
    }
    __syncthreads();

    // ---- phase 4: stage-2 GEMM, no barriers ----
    f32x4 acc2[2][2] = {};
#pragma unroll
    for (int ks = 0; ks < 8; ++ks){
        int kt = ks * 32;
        short8 ah[2], al[2], bh[2], bl[2];
#pragma unroll
        for (int mi = 0; mi < 2; ++mi){
            int row = wr * 32 + mi * 16 + lr;
            ah[mi] = *reinterpret_cast<const short8*>(&As_h[row][kt + lk]);
            al[mi] = *reinterpret_cast<const short8*>(&As_l[row][kt + lk]);
        }
#pragma unroll
        for (int ni = 0; ni < 2; ++ni){
            size_t off = ((size_t)((wc * 2 + ni) * 8 + ks) << 9) + l * 8;
            bh[ni] = *reinterpret_cast<const short8*>(&W2h[off]);
            bl[ni] = *reinterpret_cast<const short8*>(&W2l[off]);
        }
#pragma unroll
        for (int mi = 0; mi < 2; ++mi)
#pragma unroll
            for (int ni = 0; ni < 2; ++ni)
                acc2[mi][ni] = __builtin_amdgcn_mfma_f32_16x16x32_bf16(ah[mi], bh[ni], acc2[mi][ni], 0, 0, 0);
#pragma unroll
        for (int mi = 0; mi < 2; ++mi)
#pragma unroll
            for (int ni = 0; ni < 2; ++ni)
                acc2[mi][ni] = __builtin_amdgcn_mfma_f32_16x16x32_bf16(ah[mi], bl[ni], acc2[mi][ni], 0, 0, 0);
#pragma unroll
        for (int mi = 0; mi < 2; ++mi)
#pragma unroll
            for (int ni = 0; ni < 2; ++ni)
                acc2[mi][ni] = __builtin_amdgcn_mfma_f32_16x16x32_bf16(al[mi], bh[ni], acc2[mi][ni], 0, 0, 0);
    }
    __syncthreads();   // done reading U

    // ---- phase 5: relu(+bd2), dot Wd3, reduce, sigmoid ----
    float* red = (float*)&As_h[0][0];   // [64][65] floats = 16.6 KB < As_h
    float psum[2][4] = {};
#pragma unroll
    for (int ni = 0; ni < 2; ++ni){
        int c = wc * 32 + ni * 16 + lr;
        float b2v = bd2[c];
        float w3v = Wd3[c];
#pragma unroll
        for (int mi = 0; mi < 2; ++mi)
#pragma unroll
            for (int rr = 0; rr < 4; ++rr)
                psum[mi][rr] += fmaxf(acc2[mi][ni][rr] + b2v, 0.f) * w3v;
    }
#pragma unroll
    for (int mi = 0; mi < 2; ++mi)
#pragma unroll
        for (int rr = 0; rr < 4; ++rr){
            int r = wr * 32 + mi * 16 + lg * 4 + rr;
            red[r * 65 + wc * 16 + lr] = psum[mi][rr];
        }
    __syncthreads();

    {
        int qr = tid >> 3, part = tid & 7;
        float s = 0.f;
#pragma unroll
        for (int j = 0; j < 8; ++j) s += red[qr * 65 + part * 8 + j];
        s += __shfl_xor(s, 1, 8);
        s += __shfl_xor(s, 2, 8);
        s += __shfl_xor(s, 4, 8);
        int q = q0 + qr;
        if (part == 0 && q < Q) out[q] = 1.f / (1.f + expf(-(s + bd3[0])));
    }
}

// ---------------- launch ----------------
extern "C" void kernel_launch(void* const* d_in, const int* in_sizes, int n_in,
                              void* d_out, int out_size, void* d_ws, size_t ws_size,
                              hipStream_t stream){
    const float* x   = (const float*)d_in[0];
    const int*   ei  = (const int*)  d_in[1];
    const int*   qe  = (const int*)  d_in[2];
    const int*   iv  = (const int*)  d_in[3];
    const int*   pid = (const int*)  d_in[4];
    const float* W1  = (const float*)d_in[5];
    const float* b1  = (const float*)d_in[6];
    const float* W2  = (const float*)d_in[7];
    const float* b2  = (const float*)d_in[8];
    const float* Wfc = (const float*)d_in[9];
    const float* bfc = (const float*)d_in[10];
    const float* Wd1 = (const float*)d_in[11];
    const float* bd1 = (const float*)d_in[12];
    const float* Wd2 = (const float*)d_in[13];
    const float* bd2 = (const float*)d_in[14];
    const float* Wd3 = (const float*)d_in[15];
    const float* bd3 = (const float*)d_in[16];
    float* out = (float*)d_out;

    const int N = in_sizes[3];
    const int E = in_sizes[1] / 2;
    const int Q = in_sizes[2] / 2;

    char* p = (char*)d_ws;
    auto alloc = [&](size_t bytes) -> char* {
        char* r = p; p += (bytes + 255) & ~(size_t)255; return r;
    };
    int*   counts  = (int*)  alloc((size_t)N * 4);
    int*   offsets = (int*)  alloc((size_t)(N + 1) * 4);
    int*   cursor  = (int*)  alloc((size_t)(N + 1) * 4);
    int*   srclist = (int*)  alloc((size_t)E * 4);
    float* dinv    = (float*)alloc((size_t)N * 4);
    int*   bsum    = (int*)  alloc(1024 * 4);
    int*   boff    = (int*)  alloc(1024 * 4);
    unsigned short* w1h  = (unsigned short*)alloc(256 * 128 * 2);
    unsigned short* w1l  = (unsigned short*)alloc(256 * 128 * 2);
    unsigned short* w2h  = (unsigned short*)alloc(256 * 256 * 2);
    unsigned short* w2l  = (unsigned short*)alloc(256 * 256 * 2);
    unsigned short* wfh  = (unsigned short*)alloc(128 * 256 * 2);
    unsigned short* wfl  = (unsigned short*)alloc(128 * 256 * 2);
    unsigned short* wd1h = (unsigned short*)alloc(256 * 256 * 2);
    unsigned short* wd1l = (unsigned short*)alloc(256 * 256 * 2);
    unsigned short* wd2h = (unsigned short*)alloc(128 * 256 * 2);
    unsigned short* wd2l = (unsigned short*)alloc(128 * 256 * 2);
    // pool A: [N][256] fp32  (h1s)  reused as  h2 split pair
    float* PA = (float*)alloc((size_t)N * 256 * 4);
    // pool B: [N][256]-fp32-equivalent bytes: ag1 pair -> ag2 pair -> z pair
    unsigned short* PB = (unsigned short*)alloc((size_t)N * 256 * 2 * 2);

    unsigned short* ag1h = PB;                         // [N][128]
    unsigned short* ag1l = PB + (size_t)N * 128;
    float*          h1s  = PA;                         // [N][256] fp32
    unsigned short* ag2h = PB;                         // [N][256] (ag1 dead)
    unsigned short* ag2l = PB + (size_t)N * 256;
    unsigned short* h2h  = (unsigned short*)PA;        // [N][256] (h1s dead)
    unsigned short* h2l  = (unsigned short*)PA + (size_t)N * 256;
    unsigned short* zh   = PB;                         // [N][128] (ag2 dead)
    unsigned short* zl   = PB + (size_t)N * 128;

    const int nb = (N + 1023) / 1024;
    dim3 blk(256);

    hipMemsetAsync(counts, 0, (size_t)N * 4, stream);
    k_count   <<<dim3((E + 255) / 256), blk,        0, stream>>>(ei, E, counts);
    k_blocksum<<<dim3(nb),              dim3(1024), 0, stream>>>(counts, N, bsum);
    k_bscan   <<<dim3(1),               dim3(64),   0, stream>>>(bsum, nb, boff, offsets, N);
    k_offsets <<<dim3(nb),              dim3(1024), 0, stream>>>(counts, N, boff, offsets, cursor, dinv);
    k_fill    <<<dim3((E + 255) / 256), blk,        0, stream>>>(ei, E, cursor, srclist);

    // weight preprocessing
    k_split_w   <<<dim3(128), blk, 0, stream>>>(W1,  w1h,  w1l,  128, 256);
    k_split_w   <<<dim3(256), blk, 0, stream>>>(W2,  w2h,  w2l,  256, 256);
    k_split_w   <<<dim3(128), blk, 0, stream>>>(Wfc, wfh,  wfl,  256, 128);
    k_split_pack<<<dim3(256), blk, 0, stream>>>(Wd1, wd1h, wd1l, 256, 256);
    k_split_pack<<<dim3(128), blk, 0, stream>>>(Wd2, wd2h, wd2l, 256, 128);

    // encoder
    k_agg2<<<dim3(N / 4), blk, 0, stream>>>(x, offsets, srclist, dinv, ag1h, ag1l, N);
    k_mgemm<true,  true,  false><<<dim3((N + 127) / 128, 2), blk, 0, stream>>>(
        ag1h, ag1l, w1h, w1l, b1, dinv, h1s, nullptr, nullptr, N, 128, 256);
    k_agg4<<<dim3(N / 4), blk, 0, stream>>>(h1s, offsets, srclist, dinv, ag2h, ag2l, N);
    k_mgemm<true,  false, true ><<<dim3((N + 127) / 128, 2), blk, 0, stream>>>(
        ag2h, ag2l, w2h, w2l, b2, nullptr, nullptr, h2h, h2l, N, 256, 256);
    k_mgemm<false, false, true ><<<dim3((N + 127) / 128, 1), blk, 0, stream>>>(
        h2h, h2l, wfh, wfl, bfc, nullptr, nullptr, zh, zl, N, 256, 128);

    // fused decoder
    k_dec<<<dim3((Q + 63) / 64), dim3(512), 0, stream>>>(zh, zl, qe, iv, pid,
                                                         wd1h, wd1l, Wd1, bd1,
                                                         wd2h, wd2l, bd2, Wd3, bd3, out, Q);
}